// Round 15
// baseline (284.549 us; speedup 1.0000x reference)
//
#include <hip/hip_runtime.h>

typedef short bf16x8 __attribute__((ext_vector_type(8)));
typedef float f32x4 __attribute__((ext_vector_type(4)));
typedef float f32x16 __attribute__((ext_vector_type(16)));
typedef unsigned int u32;
typedef u32 u32x4 __attribute__((ext_vector_type(4)));
typedef unsigned short u16;

#define B_    32
#define N_    1025
#define H_    8
#define DIM_  512
#define M_    (B_*N_)      // 32800
#define QP_   1152         // qn row pitch per bh
#define BIP_  1152         // bias_r i pitch
#define NT_   34           // KV/bias tiles incl. 1 pad tile (prefetch guard-free)
#define KVSZ_ (NT_*2048)   // per-bh u16 size of kn2/v2
#define BT_   (BIP_*32)    // bias tile stride (u16 elements)
#define SCALE_ 0.125f
#define LOG2E_ 1.4426950408889634f

// fused-prep section sizes
#define CONVN_ (M_*DIM_/4)          // 4,198,400
#define TQKV_  (512*1536)           // 786,432
#define TOUT_  (512*512)            // 262,144
#define NBIAS_ (8*NT_*1152*32)      // 10,027,008
#define NZT_   3096576
#define PREP_TOTAL_ (CONVN_+TQKV_+TOUT_+NBIAS_+NZT_)   // 18,370,560 -> 71,760 blocks

__device__ __forceinline__ u16 f2bf(float f){
  unsigned u = __builtin_bit_cast(unsigned, f);
  u += 0x7FFFu + ((u >> 16) & 1u);
  return (u16)(u >> 16);
}
__device__ __forceinline__ u32 cvtpk(float a, float b){
  u32 r;
  asm("v_cvt_pk_bf16_f32 %0, %1, %2" : "=v"(r) : "v"(a), "v"(b));
  return r;
}
__device__ __forceinline__ void pswap(u32 &a, u32 &b){
  asm("v_permlane32_swap_b32 %0, %1" : "+v"(a), "+v"(b));
}
__device__ __forceinline__ void gll16(const u16* g, u16* l){
  __builtin_amdgcn_global_load_lds((const __attribute__((address_space(1))) u16*)(g),
                                   (__attribute__((address_space(3))) u16*)(l), 16, 0, 0);
}

// ---------------- fused prep kernel ----------------
__global__ __launch_bounds__(256)
void k_prep(const float* __restrict__ x, const float* __restrict__ wqkv,
            const float* __restrict__ wout, const int* __restrict__ idx,
            const float* __restrict__ pe,
            u16* __restrict__ xb, u16* __restrict__ wT, u16* __restrict__ woT,
            u16* __restrict__ br,
            u16* __restrict__ qn, u16* __restrict__ kn2, u16* __restrict__ v2){
  int i = blockIdx.x*256 + threadIdx.x;
  if (i < CONVN_){
    float4 v = ((const float4*)x)[i];
    ushort4 r;
    r.x = f2bf(v.x); r.y = f2bf(v.y); r.z = f2bf(v.z); r.w = f2bf(v.w);
    ((ushort4*)xb)[i] = r;
  } else if (i < CONVN_+TQKV_){
    int j = i - CONVN_;
    int n = j / 512, k = j - n*512;
    wT[j] = f2bf(wqkv[k*1536 + n]);
  } else if (i < CONVN_+TQKV_+TOUT_){
    int j = i - (CONVN_+TQKV_);
    int n = j / 512, k = j - n*512;
    woT[j] = f2bf(wout[k*512 + n]);
  } else if (i < CONVN_+TQKV_+TOUT_+NBIAS_){
    int j = i - (CONVN_+TQKV_+TOUT_);
    int v = j & 15, hi = (j>>4)&1;
    int t1 = j >> 5;
    int ii = t1 % 1152;
    int t2 = t1 / 1152;
    int tj = t2 % NT_;
    int h = t2 / NT_;
    int jj = tj*32 + (v&3) + 8*(v>>2) + 4*hi;
    float val;
    if (jj >= 1 && jj <= 1024 && ii >= 1 && ii <= 1024)
      val = pe[idx[(ii-1)*1024 + (jj-1)]*8 + h] * LOG2E_;
    else
      val = (jj <= 1024) ? 0.f : -1e9f;
    br[j] = f2bf(val);
  } else {
    int j = i - (CONVN_+TQKV_+TOUT_+NBIAS_);
    if (j < 2080768){
      int bh = j / (127*64); int r = j - bh*(127*64);
      qn[((size_t)bh*QP_ + 1025 + (r>>6))*64 + (r&63)] = 0;
    } else if (j < 2588672){
      int k = j - 2080768; int bh = k/1984; int r = k - bh*1984;
      int n = 1025 + (r>>6), d = r & 63;
      kn2[(size_t)bh*KVSZ_ + 65536 + ((d>>3)<<8) + ((n&31)<<3) + (d&7)] = 0;
    } else if (j < 3096576){
      int k = j - 2588672; int bh = k/1984; int r = k - bh*1984;
      int n = 1025 + (r>>6), d = r & 63;
      v2[(size_t)bh*KVSZ_ + 65536 + (((n>>3)&3)<<9) + (d<<3) + (n&7)] = 0;
    }
  }
}

// ---------------- QKV GEMM (128x128 tile) + fused RMSNorm / rearrange ----------------
// grid 3084 = 257 M-tiles x 12 N-tiles; 4 waves 2x2, each 64x64 quadrant
__global__ __launch_bounds__(256, 4)
void k_qkv(const u16* __restrict__ xb, const u16* __restrict__ wT, const float* __restrict__ g,
           u16* __restrict__ qn, u16* __restrict__ kn2, u16* __restrict__ v2){
  __shared__ u16 sh[16384];   // As[2][4096] | Bs[2][4096]
  const int tid = threadIdx.x;
  const int lane = tid & 63, wid = tid >> 6;
  const int lg = lane >> 4, lr = lane & 15;
  const int wm = wid >> 1, wn = wid & 1;

  // bijective XCD swizzle (nwg=3084, q=385, r=4); within XCD: nt fastest
  int orig = blockIdx.x;
  int xcd = orig & 7, idx = orig >> 3;
  int wgid = (xcd < 4 ? xcd*386 : 1544 + (xcd-4)*385) + idx;
  int mt = wgid / 12, nt = wgid - mt*12;
  const int m0 = mt*128, n0 = nt*128;
  const int qkv_t = nt >> 2;
  const int h = ((nt & 3) << 1) + wn;

  const int srow = tid >> 2;
  const int schunk = (tid & 3) ^ ((tid >> 3) & 3);
  const u16* asrc = xb + (size_t)(m0 + srow)*DIM_ + schunk*8;
  const u16* bsrc = wT + (size_t)(n0 + srow)*DIM_ + schunk*8;
  const int rsw = (lg ^ ((lr>>1)&3)) << 3;

  u16* As = sh;
  u16* Bs = sh + 8192;

  f32x4 acc[4][4];
#pragma unroll
  for (int m=0;m<4;++m)
#pragma unroll
    for (int n=0;n<4;++n) acc[m][n] = {0.f,0.f,0.f,0.f};

  gll16(asrc,            As + wid*512);
  gll16(asrc + 64*DIM_,  As + 2048 + wid*512);
  gll16(bsrc,            Bs + wid*512);
  gll16(bsrc + 64*DIM_,  Bs + 2048 + wid*512);

  for (int s=0; s<16; ++s){
    const int cur = s & 1;
    __syncthreads();
    if (s < 15){
      const int ko = (s+1)*32;
      gll16(asrc + ko,           As + (cur^1)*4096 + wid*512);
      gll16(asrc + ko + 64*DIM_, As + (cur^1)*4096 + 2048 + wid*512);
      gll16(bsrc + ko,           Bs + (cur^1)*4096 + wid*512);
      gll16(bsrc + ko + 64*DIM_, Bs + (cur^1)*4096 + 2048 + wid*512);
    }
    bf16x8 af[4], bf[4];
#pragma unroll
    for (int m=0;m<4;++m) af[m] = *(const bf16x8*)(As + cur*4096 + (64*wm+16*m+lr)*32 + rsw);
#pragma unroll
    for (int n=0;n<4;++n) bf[n] = *(const bf16x8*)(Bs + cur*4096 + (64*wn+16*n+lr)*32 + rsw);
    __builtin_amdgcn_s_setprio(1);
#pragma unroll
    for (int m=0;m<4;++m)
#pragma unroll
      for (int n=0;n<4;++n)
        acc[m][n] = __builtin_amdgcn_mfma_f32_16x16x32_bf16(af[m], bf[n], acc[m][n], 0, 0, 0);
    __builtin_amdgcn_s_setprio(0);
  }

  // unified epilogue: rows 64*wm+16m+4lg+r, head h, d = 16n+lr
  float gv[4];
#pragma unroll
  for (int n=0;n<4;++n)
    gv[n] = (qkv_t==0) ? g[16*n+lr]*(SCALE_*LOG2E_) : (qkv_t==1 ? g[16*n+lr] : 1.f);

#pragma unroll
  for (int m=0;m<4;++m){
    float rstd[4];
    if (qkv_t < 2){
#pragma unroll
      for (int r=0;r<4;++r){
        float s = 0.f;
#pragma unroll
        for (int n=0;n<4;++n) s += acc[m][n][r]*acc[m][n][r];
        s += __shfl_xor(s, 1); s += __shfl_xor(s, 2);
        s += __shfl_xor(s, 4); s += __shfl_xor(s, 8);
        rstd[r] = rsqrtf(s*(1.f/64.f) + 1e-6f);
      }
    } else {
#pragma unroll
      for (int r=0;r<4;++r) rstd[r] = 1.f;
    }
#pragma unroll
    for (int r=0;r<4;++r){
      int mg = m0 + 64*wm + 16*m + 4*lg + r;
      if (mg < M_){
        int b = mg / N_, pos = mg - b*N_;
        int bh = b*H_ + h;
#pragma unroll
        for (int n=0;n<4;++n){
          int d = 16*n + lr;
          u16 val = f2bf(acc[m][n][r]*rstd[r]*gv[n]);
          if (qkv_t == 0)
            qn[((size_t)bh*QP_ + pos)*64 + d] = val;
          else if (qkv_t == 1)
            kn2[(size_t)bh*KVSZ_ + (pos>>5)*2048 + ((d>>3)<<8) + ((pos&31)<<3) + (d&7)] = val;
          else
            v2[(size_t)bh*KVSZ_ + (pos>>5)*2048 + (((pos>>3)&3)<<9) + (d<<3) + (pos&7)] = val;
        }
      }
    }
  }
}

// ---------------- flash attention (merged main + cls) ----------------
// TILEP: verified tile body; QK split into 2 independent MFMA chains (latency ILP)
#define TILEP(kb, vb, B0, B1) do { \
  f32x16 s, sB_; \
  _Pragma("unroll") \
  for (int r=0;r<16;++r){ \
    u16 bv = (r < 8) ? ((u16)(B0)[r]) : ((u16)(B1)[r-8]); \
    s[r] = __builtin_bit_cast(float, ((u32)bv) << 16); \
    sB_[r] = 0.f; \
  } \
  __builtin_amdgcn_s_setprio(1); \
  { \
    bf16x8 kf0 = *(const bf16x8*)((kb) + (0 + hi)*256 + il*8); \
    bf16x8 kf1 = *(const bf16x8*)((kb) + (2 + hi)*256 + il*8); \
    bf16x8 kf2 = *(const bf16x8*)((kb) + (4 + hi)*256 + il*8); \
    bf16x8 kf3 = *(const bf16x8*)((kb) + (6 + hi)*256 + il*8); \
    s   = __builtin_amdgcn_mfma_f32_32x32x16_bf16(kf0, qf[0], s,   0, 0, 0); \
    sB_ = __builtin_amdgcn_mfma_f32_32x32x16_bf16(kf2, qf[2], sB_, 0, 0, 0); \
    s   = __builtin_amdgcn_mfma_f32_32x32x16_bf16(kf1, qf[1], s,   0, 0, 0); \
    sB_ = __builtin_amdgcn_mfma_f32_32x32x16_bf16(kf3, qf[3], sB_, 0, 0, 0); \
  } \
  __builtin_amdgcn_s_setprio(0); \
  _Pragma("unroll") \
  for (int r=0;r<16;++r) s[r] = __builtin_amdgcn_exp2f(s[r] + sB_[r]); \
  u32 X0 = cvtpk(s[0],s[1]),   X1 = cvtpk(s[2],s[3]); \
  u32 Y0 = cvtpk(s[4],s[5]),   Y1 = cvtpk(s[6],s[7]); \
  u32 X2 = cvtpk(s[8],s[9]),   X3 = cvtpk(s[10],s[11]); \
  u32 Y2 = cvtpk(s[12],s[13]), Y3 = cvtpk(s[14],s[15]); \
  pswap(X0, Y0); pswap(X1, Y1); pswap(X2, Y2); pswap(X3, Y3); \
  u32x4 w0 = {X0, X1, Y0, Y1}; \
  u32x4 w1 = {X2, X3, Y2, Y3}; \
  bf16x8 pv0 = __builtin_bit_cast(bf16x8, w0); \
  bf16x8 pv1 = __builtin_bit_cast(bf16x8, w1); \
  __builtin_amdgcn_s_setprio(1); \
  _Pragma("unroll") \
  for (int c2=0;c2<2;++c2){ \
    bf16x8 pv = c2 ? pv1 : pv0; \
    const u16* vb2 = (vb) + (2*c2 + hi)*512; \
    bf16x8 vfA = *(const bf16x8*)(vb2 + il*8); \
    bf16x8 vfB = *(const bf16x8*)(vb2 + 256 + il*8); \
    oA = __builtin_amdgcn_mfma_f32_32x32x16_bf16(vfA, pv, oA, 0, 0, 0); \
    oB = __builtin_amdgcn_mfma_f32_32x32x16_bf16(vfB, pv, oB, 0, 0, 0); \
    oS = __builtin_amdgcn_mfma_f32_32x32x16_bf16(onesf, pv, oS, 0, 0, 0); \
  } \
  __builtin_amdgcn_s_setprio(0); \
} while(0)

// grid 2304: blocks [0,2048) = main (8 XCD-chunks x 32 b x 8 qt, rows 0..1023);
// blocks [2048,2304) = cls row 1024, split-j over 4 waves (single-buffer 4-tile rounds)
__global__ __launch_bounds__(256, 3)
void k_attn2(const u16* __restrict__ qn, const u16* __restrict__ kn2, const u16* __restrict__ v2,
             const u16* __restrict__ br, u16* __restrict__ ao){
  __shared__ u16 sh[16384];          // main: K[2][4096] | V[2][4096]; cls: K[4][2048] | V[4][2048]
  __shared__ float red[4][2][33];
  const int tid = threadIdx.x;
  const int lane = tid & 63, wave = tid >> 6;
  const int il = lane & 31, hi = lane >> 5;
  u16* shK = sh;
  u16* shV = sh + 8192;

  f32x16 oA, oB, oS;
#pragma unroll
  for (int r=0;r<16;++r){ oA[r]=0.f; oB[r]=0.f; oS[r]=0.f; }
  const bf16x8 onesf = {0x3F80,0x3F80,0x3F80,0x3F80,0x3F80,0x3F80,0x3F80,0x3F80};

  if (blockIdx.x < 2048){
    // ---------------- main path ----------------
    int wg = ((blockIdx.x & 7) << 8) + (blockIdx.x >> 3);
    int h = wg >> 8;
    int rem = wg & 255;
    int b = rem >> 3, qt = rem & 7;
    int bh = b*8 + h;
    int i0 = qt*128 + wave*32;   // <= 992: all rows real

    const u16* qp = qn + ((size_t)bh*QP_ + (i0 + il))*64 + hi*8;
    bf16x8 qf[4];
#pragma unroll
    for (int c=0;c<4;++c) qf[c] = *(const bf16x8*)(qp + 16*c);

    const u16* ksrc = kn2 + (size_t)bh*KVSZ_ + tid*8;
    const u16* vsrc = v2  + (size_t)bh*KVSZ_ + tid*8;

    gll16(ksrc,        shK + wave*512);
    gll16(ksrc + 2048, shK + 2048 + wave*512);
    gll16(vsrc,        shV + wave*512);
    gll16(vsrc + 2048, shV + 2048 + wave*512);

    const u16* bptr = br + ((size_t)(h*NT_)*BIP_ + (i0 + il))*32 + hi*16;
    bf16x8 cb0 = *(const bf16x8*)(bptr);
    bf16x8 cb1 = *(const bf16x8*)(bptr + 8);
    bf16x8 cb2 = *(const bf16x8*)(bptr + BT_);
    bf16x8 cb3 = *(const bf16x8*)(bptr + BT_ + 8);

    for (int t=0; t<16; ++t){
      const int cur = t & 1;
      __syncthreads();
      {
        const int base = (2*t+2)*2048;   // t=15 -> tiles 32,33 (pad tile valid)
        gll16(ksrc + base,        shK + (cur^1)*4096 + wave*512);
        gll16(ksrc + base + 2048, shK + (cur^1)*4096 + 2048 + wave*512);
        gll16(vsrc + base,        shV + (cur^1)*4096 + wave*512);
        gll16(vsrc + base + 2048, shV + (cur^1)*4096 + 2048 + wave*512);
      }
      TILEP(shK + cur*4096,        shV + cur*4096,        cb0, cb1);
      cb0 = *(const bf16x8*)(bptr + 2*BT_);
      cb1 = *(const bf16x8*)(bptr + 2*BT_ + 8);
      TILEP(shK + cur*4096 + 2048, shV + cur*4096 + 2048, cb2, cb3);
      cb2 = *(const bf16x8*)(bptr + 3*BT_);
      cb3 = *(const bf16x8*)(bptr + 3*BT_ + 8);
      bptr += 2*BT_;
    }
    __syncthreads();
    TILEP(shK, shV, cb0, cb1);   // tail: tile 32 in buf 0

    float inv = 1.f / oS[0];
    int i = i0 + il;
    u16* op = ao + ((size_t)(b*N_ + i))*DIM_ + h*64;
#pragma unroll
    for (int q=0;q<4;++q)
#pragma unroll
      for (int pr=0;pr<2;++pr){
        int d0 = 8*q + 4*hi + 2*pr;
        u32 wA = cvtpk(oA[4*q+2*pr]*inv, oA[4*q+2*pr+1]*inv);
        u32 wB = cvtpk(oB[4*q+2*pr]*inv, oB[4*q+2*pr+1]*inv);
        *(u32*)(op + d0) = wA;
        *(u32*)(op + 32 + d0) = wB;
      }
  } else {
    // ---------------- cls path: row 1024, split-j over 4 waves ----------------
    int idx2 = blockIdx.x - 2048;       // 0..255; xcd = idx2&7 = h (bias locality)
    int h = idx2 & 7, b = idx2 >> 3;
    int bh = b*8 + h;

    const u16* qp = qn + ((size_t)bh*QP_ + (1024 + il))*64 + hi*8;
    bf16x8 qf[4];
#pragma unroll
    for (int c=0;c<4;++c) qf[c] = *(const bf16x8*)(qp + 16*c);

    const u16* ksrc = kn2 + (size_t)bh*KVSZ_ + tid*8;
    const u16* vsrc = v2  + (size_t)bh*KVSZ_ + tid*8;

    for (int rr=0; rr<9; ++rr){
      __syncthreads();       // previous round's compute done
#pragma unroll
      for (int tt=0;tt<4;++tt){
        int t = 4*rr + tt;
        if (t < NT_){
          gll16(ksrc + t*2048, shK + tt*2048 + wave*512);
          gll16(vsrc + t*2048, shV + tt*2048 + wave*512);
        }
      }
      __syncthreads();       // staging landed (vmcnt drained by barrier)
      const int t = 4*rr + wave;
      if (t <= 32){
        const u16* bp2 = br + ((size_t)(h*NT_ + t)*BIP_ + (1024 + il))*32 + hi*16;
        bf16x8 c0 = *(const bf16x8*)(bp2);
        bf16x8 c1 = *(const bf16x8*)(bp2 + 8);
        TILEP(shK + wave*2048, shV + wave*2048, c0, c1);
      }
    }

    // combine 4 waves' disjoint-tile partials (lanes il==0, hi=0/1)
    if (il == 0){
#pragma unroll
      for (int r=0;r<16;++r){
        red[wave][hi][r]      = oA[r];
        red[wave][hi][16 + r] = oB[r];
      }
      red[wave][hi][32] = oS[0];
    }
    __syncthreads();
    if (tid < 64){
      int d = tid;
      int half = d >> 5;
      int dd = d & 31;
      int q = dd >> 3, h2 = (dd >> 2) & 1, pr = (dd >> 1) & 1, e = dd & 1;
      int reg = half*16 + 4*q + 2*pr + e;
      float v = 0.f, ls = 0.f;
#pragma unroll
      for (int w=0; w<4; ++w){ v += red[w][h2][reg]; ls += red[w][0][32]; }
      ao[((size_t)(b*N_ + 1024))*DIM_ + h*64 + d] = f2bf(v / ls);
    }
  }
}

// ---------------- output projection (128x128 tile) ----------------
// grid 1028 = 257 x 4
__global__ __launch_bounds__(256)
void k_oproj(const u16* __restrict__ ab, const u16* __restrict__ wT, const float* __restrict__ bo,
             float* __restrict__ out){
  __shared__ u16 sh[16384];
  const int tid = threadIdx.x;
  const int lane = tid & 63, wid = tid >> 6;
  const int lg = lane >> 4, lr = lane & 15;
  const int wm = wid >> 1, wn = wid & 1;

  // bijective XCD swizzle (nwg=1028, q=128, r=4)
  int orig = blockIdx.x;
  int xcd = orig & 7, idx = orig >> 3;
  int wgid = (xcd < 4 ? xcd*129 : 516 + (xcd-4)*128) + idx;
  int mt = wgid >> 2, nt = wgid & 3;
  const int m0 = mt*128, n0 = nt*128;

  const int srow = tid >> 2;
  const int schunk = (tid & 3) ^ ((tid >> 3) & 3);
  const u16* asrc = ab + (size_t)(m0 + srow)*DIM_ + schunk*8;
  const u16* bsrc = wT + (size_t)(n0 + srow)*DIM_ + schunk*8;
  const int rsw = (lg ^ ((lr>>1)&3)) << 3;

  u16* As = sh;
  u16* Bs = sh + 8192;

  f32x4 acc[4][4];
#pragma unroll
  for (int m=0;m<4;++m)
#pragma unroll
    for (int n=0;n<4;++n) acc[m][n] = {0.f,0.f,0.f,0.f};

  gll16(asrc,            As + wid*512);
  gll16(asrc + 64*DIM_,  As + 2048 + wid*512);
  gll16(bsrc,            Bs + wid*512);
  gll16(bsrc + 64*DIM_,  Bs + 2048 + wid*512);

  for (int s=0; s<16; ++s){
    const int cur = s & 1;
    __syncthreads();
    if (s < 15){
      const int ko = (s+1)*32;
      gll16(asrc + ko,           As + (cur^1)*4096 + wid*512);
      gll16(asrc + ko + 64*DIM_, As + (cur^1)*4096 + 2048 + wid*512);
      gll16(bsrc + ko,           Bs + (cur^1)*4096 + wid*512);
      gll16(bsrc + ko + 64*DIM_, Bs + (cur^1)*4096 + 2048 + wid*512);
    }
    bf16x8 af[4], bf[4];
#pragma unroll
    for (int m=0;m<4;++m) af[m] = *(const bf16x8*)(As + cur*4096 + (64*wm+16*m+lr)*32 + rsw);
#pragma unroll
    for (int n=0;n<4;++n) bf[n] = *(const bf16x8*)(Bs + cur*4096 + (64*wn+16*n+lr)*32 + rsw);
    __builtin_amdgcn_s_setprio(1);
#pragma unroll
    for (int m=0;m<4;++m)
#pragma unroll
      for (int n=0;n<4;++n)
        acc[m][n] = __builtin_amdgcn_mfma_f32_16x16x32_bf16(af[m], bf[n], acc[m][n], 0, 0, 0);
    __builtin_amdgcn_s_setprio(0);
  }

  float bb[4];
#pragma unroll
  for (int n=0;n<4;++n) bb[n] = bo[n0 + 64*wn + 16*n + lr];
#pragma unroll
  for (int m=0;m<4;++m)
#pragma unroll
    for (int r=0;r<4;++r){
      int mg = m0 + 64*wm + 16*m + 4*lg + r;
      if (mg < M_){
#pragma unroll
        for (int n=0;n<4;++n)
          out[(size_t)mg*DIM_ + n0 + 64*wn + 16*n + lr] = acc[m][n][r] + bb[n];
      }
    }
}

// ---------------- launch ----------------
extern "C" void kernel_launch(void* const* d_in, const int* in_sizes, int n_in,
                              void* d_out, int out_size, void* d_ws, size_t ws_size,
                              hipStream_t stream) {
  const float* x     = (const float*)d_in[0];
  const float* w_qkv = (const float*)d_in[1];
  const float* g     = (const float*)d_in[2];
  const float* pe    = (const float*)d_in[3];
  const float* w_out = (const float*)d_in[4];
  const float* b_out = (const float*)d_in[5];
  const int*   bidx  = (const int*)d_in[6];
  float* out = (float*)d_out;

  char* ws = (char*)d_ws;
  u16*   xb    = (u16*)(ws);                    // 33,587,200  (aliased: aob reuses after k_qkv)
  u16*   wT    = (u16*)(ws + 33587200);         //  1,572,864
  u16*   woT   = (u16*)(ws + 35160064);         //    524,288
  u16*   qnb   = (u16*)(ws + 35684352);         // 37,748,736
  u16*   kn2   = (u16*)(ws + 73433088);         // 35,651,584
  u16*   v2    = (u16*)(ws + 109084672);        // 35,651,584
  u16*   biasr = (u16*)(ws + 144736256);        // 20,054,016  (end 164,790,272)
  u16*   aob   = xb;                            // alias: xb dead after k_qkv

  k_prep<<<PREP_TOTAL_/256, 256, 0, stream>>>(x, w_qkv, w_out, bidx, pe,
                                              xb, wT, woT, biasr, qnb, kn2, v2);
  k_qkv<<<3084, 256, 0, stream>>>(xb, wT, g, qnb, kn2, v2);
  k_attn2<<<2304, 256, 0, stream>>>(qnb, kn2, v2, biasr, aob);
  k_oproj<<<1028, 256, 0, stream>>>(aob, woT, b_out, out);
}

// Round 16
// 276.058 us; speedup vs baseline: 1.0308x; 1.0308x over previous
//
#include <hip/hip_runtime.h>

typedef short bf16x8 __attribute__((ext_vector_type(8)));
typedef float f32x4 __attribute__((ext_vector_type(4)));
typedef float f32x16 __attribute__((ext_vector_type(16)));
typedef unsigned int u32;
typedef u32 u32x4 __attribute__((ext_vector_type(4)));
typedef unsigned short u16;

#define B_    32
#define N_    1025
#define H_    8
#define DIM_  512
#define M_    (B_*N_)      // 32800
#define QP_   1152         // qn row pitch per bh
#define BIP_  1152         // bias_r i pitch
#define NT_   34           // KV/bias tiles incl. 1 pad tile (prefetch guard-free)
#define KVSZ_ (NT_*2048)   // per-bh u16 size of kn2/v2
#define BT_   (BIP_*32)    // bias tile stride (u16 elements)
#define SCALE_ 0.125f
#define LOG2E_ 1.4426950408889634f

// fused-prep section sizes
#define CONVN_ (M_*DIM_/4)          // 4,198,400
#define TQKV_  (512*1536)           // 786,432
#define TOUT_  (512*512)            // 262,144
#define NBIAS_ (8*NT_*1152*32)      // 10,027,008
#define NZT_   3096576
#define PREP_TOTAL_ (CONVN_+TQKV_+TOUT_+NBIAS_+NZT_)   // 18,370,560 -> 71,760 blocks

__device__ __forceinline__ u16 f2bf(float f){
  unsigned u = __builtin_bit_cast(unsigned, f);
  u += 0x7FFFu + ((u >> 16) & 1u);
  return (u16)(u >> 16);
}
__device__ __forceinline__ u32 cvtpk(float a, float b){
  u32 r;
  asm("v_cvt_pk_bf16_f32 %0, %1, %2" : "=v"(r) : "v"(a), "v"(b));
  return r;
}
__device__ __forceinline__ void pswap(u32 &a, u32 &b){
  asm("v_permlane32_swap_b32 %0, %1" : "+v"(a), "+v"(b));
}
__device__ __forceinline__ void gll16(const u16* g, u16* l){
  __builtin_amdgcn_global_load_lds((const __attribute__((address_space(1))) u16*)(g),
                                   (__attribute__((address_space(3))) u16*)(l), 16, 0, 0);
}

// ---------------- fused prep kernel ----------------
__global__ __launch_bounds__(256)
void k_prep(const float* __restrict__ x, const float* __restrict__ wqkv,
            const float* __restrict__ wout, const int* __restrict__ idx,
            const float* __restrict__ pe,
            u16* __restrict__ xb, u16* __restrict__ wT, u16* __restrict__ woT,
            u16* __restrict__ br,
            u16* __restrict__ qn, u16* __restrict__ kn2, u16* __restrict__ v2){
  int i = blockIdx.x*256 + threadIdx.x;
  if (i < CONVN_){
    float4 v = ((const float4*)x)[i];
    ushort4 r;
    r.x = f2bf(v.x); r.y = f2bf(v.y); r.z = f2bf(v.z); r.w = f2bf(v.w);
    ((ushort4*)xb)[i] = r;
  } else if (i < CONVN_+TQKV_){
    int j = i - CONVN_;
    int n = j / 512, k = j - n*512;
    wT[j] = f2bf(wqkv[k*1536 + n]);
  } else if (i < CONVN_+TQKV_+TOUT_){
    int j = i - (CONVN_+TQKV_);
    int n = j / 512, k = j - n*512;
    woT[j] = f2bf(wout[k*512 + n]);
  } else if (i < CONVN_+TQKV_+TOUT_+NBIAS_){
    int j = i - (CONVN_+TQKV_+TOUT_);
    int v = j & 15, hi = (j>>4)&1;
    int t1 = j >> 5;
    int ii = t1 % 1152;
    int t2 = t1 / 1152;
    int tj = t2 % NT_;
    int h = t2 / NT_;
    int jj = tj*32 + (v&3) + 8*(v>>2) + 4*hi;
    float val;
    if (jj >= 1 && jj <= 1024 && ii >= 1 && ii <= 1024)
      val = pe[idx[(ii-1)*1024 + (jj-1)]*8 + h] * LOG2E_;
    else
      val = (jj <= 1024) ? 0.f : -1e9f;
    br[j] = f2bf(val);
  } else {
    int j = i - (CONVN_+TQKV_+TOUT_+NBIAS_);
    if (j < 2080768){
      int bh = j / (127*64); int r = j - bh*(127*64);
      qn[((size_t)bh*QP_ + 1025 + (r>>6))*64 + (r&63)] = 0;
    } else if (j < 2588672){
      int k = j - 2080768; int bh = k/1984; int r = k - bh*1984;
      int n = 1025 + (r>>6), d = r & 63;
      kn2[(size_t)bh*KVSZ_ + 65536 + ((d>>3)<<8) + ((n&31)<<3) + (d&7)] = 0;
    } else if (j < 3096576){
      int k = j - 2588672; int bh = k/1984; int r = k - bh*1984;
      int n = 1025 + (r>>6), d = r & 63;
      v2[(size_t)bh*KVSZ_ + 65536 + (((n>>3)&3)<<9) + (d<<3) + (n&7)] = 0;
    }
  }
}

// ---------------- QKV GEMM (128x128 tile) + fused RMSNorm / rearrange ----------------
// grid 3084 = 257 M-tiles x 12 N-tiles; 4 waves 2x2, each 64x64 quadrant
__global__ __launch_bounds__(256, 4)
void k_qkv(const u16* __restrict__ xb, const u16* __restrict__ wT, const float* __restrict__ g,
           u16* __restrict__ qn, u16* __restrict__ kn2, u16* __restrict__ v2){
  __shared__ u16 sh[16384];   // As[2][4096] | Bs[2][4096]
  const int tid = threadIdx.x;
  const int lane = tid & 63, wid = tid >> 6;
  const int lg = lane >> 4, lr = lane & 15;
  const int wm = wid >> 1, wn = wid & 1;

  // bijective XCD swizzle (nwg=3084, q=385, r=4); within XCD: nt fastest
  int orig = blockIdx.x;
  int xcd = orig & 7, idx = orig >> 3;
  int wgid = (xcd < 4 ? xcd*386 : 1544 + (xcd-4)*385) + idx;
  int mt = wgid / 12, nt = wgid - mt*12;
  const int m0 = mt*128, n0 = nt*128;
  const int qkv_t = nt >> 2;
  const int h = ((nt & 3) << 1) + wn;

  const int srow = tid >> 2;
  const int schunk = (tid & 3) ^ ((tid >> 3) & 3);
  const u16* asrc = xb + (size_t)(m0 + srow)*DIM_ + schunk*8;
  const u16* bsrc = wT + (size_t)(n0 + srow)*DIM_ + schunk*8;
  const int rsw = (lg ^ ((lr>>1)&3)) << 3;

  u16* As = sh;
  u16* Bs = sh + 8192;

  f32x4 acc[4][4];
#pragma unroll
  for (int m=0;m<4;++m)
#pragma unroll
    for (int n=0;n<4;++n) acc[m][n] = {0.f,0.f,0.f,0.f};

  gll16(asrc,            As + wid*512);
  gll16(asrc + 64*DIM_,  As + 2048 + wid*512);
  gll16(bsrc,            Bs + wid*512);
  gll16(bsrc + 64*DIM_,  Bs + 2048 + wid*512);

  for (int s=0; s<16; ++s){
    const int cur = s & 1;
    __syncthreads();
    if (s < 15){
      const int ko = (s+1)*32;
      gll16(asrc + ko,           As + (cur^1)*4096 + wid*512);
      gll16(asrc + ko + 64*DIM_, As + (cur^1)*4096 + 2048 + wid*512);
      gll16(bsrc + ko,           Bs + (cur^1)*4096 + wid*512);
      gll16(bsrc + ko + 64*DIM_, Bs + (cur^1)*4096 + 2048 + wid*512);
    }
    bf16x8 af[4], bf[4];
#pragma unroll
    for (int m=0;m<4;++m) af[m] = *(const bf16x8*)(As + cur*4096 + (64*wm+16*m+lr)*32 + rsw);
#pragma unroll
    for (int n=0;n<4;++n) bf[n] = *(const bf16x8*)(Bs + cur*4096 + (64*wn+16*n+lr)*32 + rsw);
    __builtin_amdgcn_s_setprio(1);
#pragma unroll
    for (int m=0;m<4;++m)
#pragma unroll
      for (int n=0;n<4;++n)
        acc[m][n] = __builtin_amdgcn_mfma_f32_16x16x32_bf16(af[m], bf[n], acc[m][n], 0, 0, 0);
    __builtin_amdgcn_s_setprio(0);
  }

  // unified epilogue: rows 64*wm+16m+4lg+r, head h, d = 16n+lr
  float gv[4];
#pragma unroll
  for (int n=0;n<4;++n)
    gv[n] = (qkv_t==0) ? g[16*n+lr]*(SCALE_*LOG2E_) : (qkv_t==1 ? g[16*n+lr] : 1.f);

#pragma unroll
  for (int m=0;m<4;++m){
    float rstd[4];
    if (qkv_t < 2){
#pragma unroll
      for (int r=0;r<4;++r){
        float s = 0.f;
#pragma unroll
        for (int n=0;n<4;++n) s += acc[m][n][r]*acc[m][n][r];
        s += __shfl_xor(s, 1); s += __shfl_xor(s, 2);
        s += __shfl_xor(s, 4); s += __shfl_xor(s, 8);
        rstd[r] = rsqrtf(s*(1.f/64.f) + 1e-6f);
      }
    } else {
#pragma unroll
      for (int r=0;r<4;++r) rstd[r] = 1.f;
    }
#pragma unroll
    for (int r=0;r<4;++r){
      int mg = m0 + 64*wm + 16*m + 4*lg + r;
      if (mg < M_){
        int b = mg / N_, pos = mg - b*N_;
        int bh = b*H_ + h;
#pragma unroll
        for (int n=0;n<4;++n){
          int d = 16*n + lr;
          u16 val = f2bf(acc[m][n][r]*rstd[r]*gv[n]);
          if (qkv_t == 0)
            qn[((size_t)bh*QP_ + pos)*64 + d] = val;
          else if (qkv_t == 1)
            kn2[(size_t)bh*KVSZ_ + (pos>>5)*2048 + ((d>>3)<<8) + ((pos&31)<<3) + (d&7)] = val;
          else
            v2[(size_t)bh*KVSZ_ + (pos>>5)*2048 + (((pos>>3)&3)<<9) + (d<<3) + (pos&7)] = val;
        }
      }
    }
  }
}

// ---------------- flash attention (merged main + cls) ----------------
// TILEP: verified tile body, base-pointer form (kb/vb = K/V tile bases in LDS)
#define TILEP(kb, vb, B0, B1) do { \
  f32x16 s; \
  _Pragma("unroll") \
  for (int r=0;r<16;++r){ \
    u16 bv = (r < 8) ? ((u16)(B0)[r]) : ((u16)(B1)[r-8]); \
    s[r] = __builtin_bit_cast(float, ((u32)bv) << 16); \
  } \
  __builtin_amdgcn_s_setprio(1); \
  _Pragma("unroll") \
  for (int c=0;c<4;++c){ \
    bf16x8 kf = *(const bf16x8*)((kb) + (2*c + hi)*256 + il*8); \
    s = __builtin_amdgcn_mfma_f32_32x32x16_bf16(kf, qf[c], s, 0, 0, 0); \
  } \
  __builtin_amdgcn_s_setprio(0); \
  _Pragma("unroll") \
  for (int r=0;r<16;++r) s[r] = __builtin_amdgcn_exp2f(s[r]); \
  u32 X0 = cvtpk(s[0],s[1]),   X1 = cvtpk(s[2],s[3]); \
  u32 Y0 = cvtpk(s[4],s[5]),   Y1 = cvtpk(s[6],s[7]); \
  u32 X2 = cvtpk(s[8],s[9]),   X3 = cvtpk(s[10],s[11]); \
  u32 Y2 = cvtpk(s[12],s[13]), Y3 = cvtpk(s[14],s[15]); \
  pswap(X0, Y0); pswap(X1, Y1); pswap(X2, Y2); pswap(X3, Y3); \
  u32x4 w0 = {X0, X1, Y0, Y1}; \
  u32x4 w1 = {X2, X3, Y2, Y3}; \
  bf16x8 pv0 = __builtin_bit_cast(bf16x8, w0); \
  bf16x8 pv1 = __builtin_bit_cast(bf16x8, w1); \
  __builtin_amdgcn_s_setprio(1); \
  _Pragma("unroll") \
  for (int c2=0;c2<2;++c2){ \
    bf16x8 pv = c2 ? pv1 : pv0; \
    const u16* vb2 = (vb) + (2*c2 + hi)*512; \
    bf16x8 vfA = *(const bf16x8*)(vb2 + il*8); \
    bf16x8 vfB = *(const bf16x8*)(vb2 + 256 + il*8); \
    oA = __builtin_amdgcn_mfma_f32_32x32x16_bf16(vfA, pv, oA, 0, 0, 0); \
    oB = __builtin_amdgcn_mfma_f32_32x32x16_bf16(vfB, pv, oB, 0, 0, 0); \
    oS = __builtin_amdgcn_mfma_f32_32x32x16_bf16(onesf, pv, oS, 0, 0, 0); \
  } \
  __builtin_amdgcn_s_setprio(0); \
} while(0)

// grid 2304: blocks [0,2048) = main (8 XCD-chunks x 32 b x 8 qt, rows 0..1023);
// blocks [2048,2304) = cls row 1024, split-j over 4 waves (single-buffer 4-tile rounds)
__global__ __launch_bounds__(256, 3)
void k_attn2(const u16* __restrict__ qn, const u16* __restrict__ kn2, const u16* __restrict__ v2,
             const u16* __restrict__ br, u16* __restrict__ ao){
  __shared__ u16 sh[16384];          // main: K[2][4096] | V[2][4096]; cls: K[4][2048] | V[4][2048]
  __shared__ float red[4][2][33];
  const int tid = threadIdx.x;
  const int lane = tid & 63, wave = tid >> 6;
  const int il = lane & 31, hi = lane >> 5;
  u16* shK = sh;
  u16* shV = sh + 8192;

  f32x16 oA, oB, oS;
#pragma unroll
  for (int r=0;r<16;++r){ oA[r]=0.f; oB[r]=0.f; oS[r]=0.f; }
  const bf16x8 onesf = {0x3F80,0x3F80,0x3F80,0x3F80,0x3F80,0x3F80,0x3F80,0x3F80};

  if (blockIdx.x < 2048){
    // ---------------- main path ----------------
    int wg = ((blockIdx.x & 7) << 8) + (blockIdx.x >> 3);
    int h = wg >> 8;
    int rem = wg & 255;
    int b = rem >> 3, qt = rem & 7;
    int bh = b*8 + h;
    int i0 = qt*128 + wave*32;   // <= 992: all rows real

    const u16* qp = qn + ((size_t)bh*QP_ + (i0 + il))*64 + hi*8;
    bf16x8 qf[4];
#pragma unroll
    for (int c=0;c<4;++c) qf[c] = *(const bf16x8*)(qp + 16*c);

    const u16* ksrc = kn2 + (size_t)bh*KVSZ_ + tid*8;
    const u16* vsrc = v2  + (size_t)bh*KVSZ_ + tid*8;

    gll16(ksrc,        shK + wave*512);
    gll16(ksrc + 2048, shK + 2048 + wave*512);
    gll16(vsrc,        shV + wave*512);
    gll16(vsrc + 2048, shV + 2048 + wave*512);

    const u16* bptr = br + ((size_t)(h*NT_)*BIP_ + (i0 + il))*32 + hi*16;
    bf16x8 cb0 = *(const bf16x8*)(bptr);
    bf16x8 cb1 = *(const bf16x8*)(bptr + 8);
    bf16x8 cb2 = *(const bf16x8*)(bptr + BT_);
    bf16x8 cb3 = *(const bf16x8*)(bptr + BT_ + 8);

    for (int t=0; t<16; ++t){
      const int cur = t & 1;
      __syncthreads();
      {
        const int base = (2*t+2)*2048;   // t=15 -> tiles 32,33 (pad tile valid)
        gll16(ksrc + base,        shK + (cur^1)*4096 + wave*512);
        gll16(ksrc + base + 2048, shK + (cur^1)*4096 + 2048 + wave*512);
        gll16(vsrc + base,        shV + (cur^1)*4096 + wave*512);
        gll16(vsrc + base + 2048, shV + (cur^1)*4096 + 2048 + wave*512);
      }
      TILEP(shK + cur*4096,        shV + cur*4096,        cb0, cb1);
      cb0 = *(const bf16x8*)(bptr + 2*BT_);
      cb1 = *(const bf16x8*)(bptr + 2*BT_ + 8);
      TILEP(shK + cur*4096 + 2048, shV + cur*4096 + 2048, cb2, cb3);
      cb2 = *(const bf16x8*)(bptr + 3*BT_);
      cb3 = *(const bf16x8*)(bptr + 3*BT_ + 8);
      bptr += 2*BT_;
    }
    __syncthreads();
    TILEP(shK, shV, cb0, cb1);   // tail: tile 32 in buf 0

    float inv = 1.f / oS[0];
    int i = i0 + il;
    u16* op = ao + ((size_t)(b*N_ + i))*DIM_ + h*64;
#pragma unroll
    for (int q=0;q<4;++q)
#pragma unroll
      for (int pr=0;pr<2;++pr){
        int d0 = 8*q + 4*hi + 2*pr;
        u32 wA = cvtpk(oA[4*q+2*pr]*inv, oA[4*q+2*pr+1]*inv);
        u32 wB = cvtpk(oB[4*q+2*pr]*inv, oB[4*q+2*pr+1]*inv);
        *(u32*)(op + d0) = wA;
        *(u32*)(op + 32 + d0) = wB;
      }
  } else {
    // ---------------- cls path: row 1024, split-j over 4 waves ----------------
    int idx2 = blockIdx.x - 2048;       // 0..255; xcd = idx2&7 = h (bias locality)
    int h = idx2 & 7, b = idx2 >> 3;
    int bh = b*8 + h;

    const u16* qp = qn + ((size_t)bh*QP_ + (1024 + il))*64 + hi*8;
    bf16x8 qf[4];
#pragma unroll
    for (int c=0;c<4;++c) qf[c] = *(const bf16x8*)(qp + 16*c);

    const u16* ksrc = kn2 + (size_t)bh*KVSZ_ + tid*8;
    const u16* vsrc = v2  + (size_t)bh*KVSZ_ + tid*8;

    for (int rr=0; rr<9; ++rr){
      __syncthreads();       // previous round's compute done
#pragma unroll
      for (int tt=0;tt<4;++tt){
        int t = 4*rr + tt;
        if (t < NT_){
          gll16(ksrc + t*2048, shK + tt*2048 + wave*512);
          gll16(vsrc + t*2048, shV + tt*2048 + wave*512);
        }
      }
      __syncthreads();       // staging landed (vmcnt drained by barrier)
      const int t = 4*rr + wave;
      if (t <= 32){
        const u16* bp2 = br + ((size_t)(h*NT_ + t)*BIP_ + (1024 + il))*32 + hi*16;
        bf16x8 c0 = *(const bf16x8*)(bp2);
        bf16x8 c1 = *(const bf16x8*)(bp2 + 8);
        TILEP(shK + wave*2048, shV + wave*2048, c0, c1);
      }
    }

    // combine 4 waves' disjoint-tile partials (lanes il==0, hi=0/1)
    if (il == 0){
#pragma unroll
      for (int r=0;r<16;++r){
        red[wave][hi][r]      = oA[r];
        red[wave][hi][16 + r] = oB[r];
      }
      red[wave][hi][32] = oS[0];
    }
    __syncthreads();
    if (tid < 64){
      int d = tid;
      int half = d >> 5;
      int dd = d & 31;
      int q = dd >> 3, h2 = (dd >> 2) & 1, pr = (dd >> 1) & 1, e = dd & 1;
      int reg = half*16 + 4*q + 2*pr + e;
      float v = 0.f, ls = 0.f;
#pragma unroll
      for (int w=0; w<4; ++w){ v += red[w][h2][reg]; ls += red[w][0][32]; }
      ao[((size_t)(b*N_ + 1024))*DIM_ + h*64 + d] = f2bf(v / ls);
    }
  }
}

// ---------------- output projection (128x128 tile) ----------------
// grid 1028 = 257 x 4
__global__ __launch_bounds__(256)
void k_oproj(const u16* __restrict__ ab, const u16* __restrict__ wT, const float* __restrict__ bo,
             float* __restrict__ out){
  __shared__ u16 sh[16384];
  const int tid = threadIdx.x;
  const int lane = tid & 63, wid = tid >> 6;
  const int lg = lane >> 4, lr = lane & 15;
  const int wm = wid >> 1, wn = wid & 1;

  // bijective XCD swizzle (nwg=1028, q=128, r=4)
  int orig = blockIdx.x;
  int xcd = orig & 7, idx = orig >> 3;
  int wgid = (xcd < 4 ? xcd*129 : 516 + (xcd-4)*128) + idx;
  int mt = wgid >> 2, nt = wgid & 3;
  const int m0 = mt*128, n0 = nt*128;

  const int srow = tid >> 2;
  const int schunk = (tid & 3) ^ ((tid >> 3) & 3);
  const u16* asrc = ab + (size_t)(m0 + srow)*DIM_ + schunk*8;
  const u16* bsrc = wT + (size_t)(n0 + srow)*DIM_ + schunk*8;
  const int rsw = (lg ^ ((lr>>1)&3)) << 3;

  u16* As = sh;
  u16* Bs = sh + 8192;

  f32x4 acc[4][4];
#pragma unroll
  for (int m=0;m<4;++m)
#pragma unroll
    for (int n=0;n<4;++n) acc[m][n] = {0.f,0.f,0.f,0.f};

  gll16(asrc,            As + wid*512);
  gll16(asrc + 64*DIM_,  As + 2048 + wid*512);
  gll16(bsrc,            Bs + wid*512);
  gll16(bsrc + 64*DIM_,  Bs + 2048 + wid*512);

  for (int s=0; s<16; ++s){
    const int cur = s & 1;
    __syncthreads();
    if (s < 15){
      const int ko = (s+1)*32;
      gll16(asrc + ko,           As + (cur^1)*4096 + wid*512);
      gll16(asrc + ko + 64*DIM_, As + (cur^1)*4096 + 2048 + wid*512);
      gll16(bsrc + ko,           Bs + (cur^1)*4096 + wid*512);
      gll16(bsrc + ko + 64*DIM_, Bs + (cur^1)*4096 + 2048 + wid*512);
    }
    bf16x8 af[4], bf[4];
#pragma unroll
    for (int m=0;m<4;++m) af[m] = *(const bf16x8*)(As + cur*4096 + (64*wm+16*m+lr)*32 + rsw);
#pragma unroll
    for (int n=0;n<4;++n) bf[n] = *(const bf16x8*)(Bs + cur*4096 + (64*wn+16*n+lr)*32 + rsw);
    __builtin_amdgcn_s_setprio(1);
#pragma unroll
    for (int m=0;m<4;++m)
#pragma unroll
      for (int n=0;n<4;++n)
        acc[m][n] = __builtin_amdgcn_mfma_f32_16x16x32_bf16(af[m], bf[n], acc[m][n], 0, 0, 0);
    __builtin_amdgcn_s_setprio(0);
  }

  float bb[4];
#pragma unroll
  for (int n=0;n<4;++n) bb[n] = bo[n0 + 64*wn + 16*n + lr];
#pragma unroll
  for (int m=0;m<4;++m)
#pragma unroll
    for (int r=0;r<4;++r){
      int mg = m0 + 64*wm + 16*m + 4*lg + r;
      if (mg < M_){
#pragma unroll
        for (int n=0;n<4;++n)
          out[(size_t)mg*DIM_ + n0 + 64*wn + 16*n + lr] = acc[m][n][r] + bb[n];
      }
    }
}

// ---------------- launch ----------------
extern "C" void kernel_launch(void* const* d_in, const int* in_sizes, int n_in,
                              void* d_out, int out_size, void* d_ws, size_t ws_size,
                              hipStream_t stream) {
  const float* x     = (const float*)d_in[0];
  const float* w_qkv = (const float*)d_in[1];
  const float* g     = (const float*)d_in[2];
  const float* pe    = (const float*)d_in[3];
  const float* w_out = (const float*)d_in[4];
  const float* b_out = (const float*)d_in[5];
  const int*   bidx  = (const int*)d_in[6];
  float* out = (float*)d_out;

  char* ws = (char*)d_ws;
  u16*   xb    = (u16*)(ws);                    // 33,587,200  (aliased: aob reuses after k_qkv)
  u16*   wT    = (u16*)(ws + 33587200);         //  1,572,864
  u16*   woT   = (u16*)(ws + 35160064);         //    524,288
  u16*   qnb   = (u16*)(ws + 35684352);         // 37,748,736
  u16*   kn2   = (u16*)(ws + 73433088);         // 35,651,584
  u16*   v2    = (u16*)(ws + 109084672);        // 35,651,584
  u16*   biasr = (u16*)(ws + 144736256);        // 20,054,016  (end 164,790,272)
  u16*   aob   = xb;                            // alias: xb dead after k_qkv

  k_prep<<<PREP_TOTAL_/256, 256, 0, stream>>>(x, w_qkv, w_out, bidx, pe,
                                              xb, wT, woT, biasr, qnb, kn2, v2);
  k_qkv<<<3084, 256, 0, stream>>>(xb, wT, g, qnb, kn2, v2);
  k_attn2<<<2304, 256, 0, stream>>>(qnb, kn2, v2, biasr, aob);
  k_oproj<<<1028, 256, 0, stream>>>(aob, woT, b_out, out);
}

// Round 17
// 272.807 us; speedup vs baseline: 1.0430x; 1.0119x over previous
//
#include <hip/hip_runtime.h>

typedef short bf16x8 __attribute__((ext_vector_type(8)));
typedef float f32x4 __attribute__((ext_vector_type(4)));
typedef float f32x16 __attribute__((ext_vector_type(16)));
typedef unsigned int u32;
typedef u32 u32x4 __attribute__((ext_vector_type(4)));
typedef unsigned short u16;

#define B_    32
#define N_    1025
#define H_    8
#define DIM_  512
#define M_    (B_*N_)      // 32800
#define QP_   1152         // qn row pitch per bh
#define BIP_  1152         // bias_r i pitch
#define NT_   34           // KV/bias tiles incl. 1 pad tile (prefetch guard-free)
#define KVSZ_ (NT_*2048)   // per-bh u16 size of kn2/v2
#define BT_   (BIP_*32)    // bias tile stride (u16 elements)
#define SCALE_ 0.125f
#define LOG2E_ 1.4426950408889634f

// fused-prep section sizes
#define CONVN_ (M_*DIM_/4)          // 4,198,400
#define TQKV_  (512*1536)           // 786,432
#define TOUT_  (512*512)            // 262,144
#define NBIAS_ (8*NT_*1152*32)      // 10,027,008
#define NZT_   3096576
#define PREP_TOTAL_ (CONVN_+TQKV_+TOUT_+NBIAS_+NZT_)   // 18,370,560 -> 71,760 blocks

__device__ __forceinline__ u16 f2bf(float f){
  unsigned u = __builtin_bit_cast(unsigned, f);
  u += 0x7FFFu + ((u >> 16) & 1u);
  return (u16)(u >> 16);
}
__device__ __forceinline__ u32 cvtpk(float a, float b){
  u32 r;
  asm("v_cvt_pk_bf16_f32 %0, %1, %2" : "=v"(r) : "v"(a), "v"(b));
  return r;
}
__device__ __forceinline__ void pswap(u32 &a, u32 &b){
  asm("v_permlane32_swap_b32 %0, %1" : "+v"(a), "+v"(b));
}
__device__ __forceinline__ void gll16(const u16* g, u16* l){
  __builtin_amdgcn_global_load_lds((const __attribute__((address_space(1))) u16*)(g),
                                   (__attribute__((address_space(3))) u16*)(l), 16, 0, 0);
}

// ---------------- fused prep kernel ----------------
__global__ __launch_bounds__(256)
void k_prep(const float* __restrict__ x, const float* __restrict__ wqkv,
            const float* __restrict__ wout, const int* __restrict__ idx,
            const float* __restrict__ pe,
            u16* __restrict__ xb, u16* __restrict__ wT, u16* __restrict__ woT,
            u16* __restrict__ br,
            u16* __restrict__ qn, u16* __restrict__ kn2, u16* __restrict__ v2){
  int i = blockIdx.x*256 + threadIdx.x;
  if (i < CONVN_){
    float4 v = ((const float4*)x)[i];
    ushort4 r;
    r.x = f2bf(v.x); r.y = f2bf(v.y); r.z = f2bf(v.z); r.w = f2bf(v.w);
    ((ushort4*)xb)[i] = r;
  } else if (i < CONVN_+TQKV_){
    int j = i - CONVN_;
    int n = j / 512, k = j - n*512;
    wT[j] = f2bf(wqkv[k*1536 + n]);
  } else if (i < CONVN_+TQKV_+TOUT_){
    int j = i - (CONVN_+TQKV_);
    int n = j / 512, k = j - n*512;
    woT[j] = f2bf(wout[k*512 + n]);
  } else if (i < CONVN_+TQKV_+TOUT_+NBIAS_){
    int j = i - (CONVN_+TQKV_+TOUT_);
    int v = j & 15, hi = (j>>4)&1;
    int t1 = j >> 5;
    int ii = t1 % 1152;
    int t2 = t1 / 1152;
    int tj = t2 % NT_;
    int h = t2 / NT_;
    int jj = tj*32 + (v&3) + 8*(v>>2) + 4*hi;
    float val;
    if (jj >= 1 && jj <= 1024 && ii >= 1 && ii <= 1024)
      val = pe[idx[(ii-1)*1024 + (jj-1)]*8 + h] * LOG2E_;
    else
      val = (jj <= 1024) ? 0.f : -1e9f;
    br[j] = f2bf(val);
  } else {
    int j = i - (CONVN_+TQKV_+TOUT_+NBIAS_);
    if (j < 2080768){
      int bh = j / (127*64); int r = j - bh*(127*64);
      qn[((size_t)bh*QP_ + 1025 + (r>>6))*64 + (r&63)] = 0;
    } else if (j < 2588672){
      int k = j - 2080768; int bh = k/1984; int r = k - bh*1984;
      int n = 1025 + (r>>6), d = r & 63;
      kn2[(size_t)bh*KVSZ_ + 65536 + ((d>>3)<<8) + ((n&31)<<3) + (d&7)] = 0;
    } else if (j < 3096576){
      int k = j - 2588672; int bh = k/1984; int r = k - bh*1984;
      int n = 1025 + (r>>6), d = r & 63;
      v2[(size_t)bh*KVSZ_ + 65536 + (((n>>3)&3)<<9) + (d<<3) + (n&7)] = 0;
    }
  }
}

// ---------------- QKV GEMM (128x128 tile) + fused RMSNorm / rearrange ----------------
// grid 3084 = 257 M-tiles x 12 N-tiles; 4 waves 2x2, each 64x64 quadrant
__global__ __launch_bounds__(256, 4)
void k_qkv(const u16* __restrict__ xb, const u16* __restrict__ wT, const float* __restrict__ g,
           u16* __restrict__ qn, u16* __restrict__ kn2, u16* __restrict__ v2){
  __shared__ u16 sh[16384];   // As[2][4096] | Bs[2][4096]
  const int tid = threadIdx.x;
  const int lane = tid & 63, wid = tid >> 6;
  const int lg = lane >> 4, lr = lane & 15;
  const int wm = wid >> 1, wn = wid & 1;

  // bijective XCD swizzle (nwg=3084, q=385, r=4); within XCD: nt fastest
  int orig = blockIdx.x;
  int xcd = orig & 7, idx = orig >> 3;
  int wgid = (xcd < 4 ? xcd*386 : 1544 + (xcd-4)*385) + idx;
  int mt = wgid / 12, nt = wgid - mt*12;
  const int m0 = mt*128, n0 = nt*128;
  const int qkv_t = nt >> 2;
  const int h = ((nt & 3) << 1) + wn;

  const int srow = tid >> 2;
  const int schunk = (tid & 3) ^ ((tid >> 3) & 3);
  const u16* asrc = xb + (size_t)(m0 + srow)*DIM_ + schunk*8;
  const u16* bsrc = wT + (size_t)(n0 + srow)*DIM_ + schunk*8;
  const int rsw = (lg ^ ((lr>>1)&3)) << 3;

  u16* As = sh;
  u16* Bs = sh + 8192;

  f32x4 acc[4][4];
#pragma unroll
  for (int m=0;m<4;++m)
#pragma unroll
    for (int n=0;n<4;++n) acc[m][n] = {0.f,0.f,0.f,0.f};

  gll16(asrc,            As + wid*512);
  gll16(asrc + 64*DIM_,  As + 2048 + wid*512);
  gll16(bsrc,            Bs + wid*512);
  gll16(bsrc + 64*DIM_,  Bs + 2048 + wid*512);

  for (int s=0; s<16; ++s){
    const int cur = s & 1;
    __syncthreads();
    if (s < 15){
      const int ko = (s+1)*32;
      gll16(asrc + ko,           As + (cur^1)*4096 + wid*512);
      gll16(asrc + ko + 64*DIM_, As + (cur^1)*4096 + 2048 + wid*512);
      gll16(bsrc + ko,           Bs + (cur^1)*4096 + wid*512);
      gll16(bsrc + ko + 64*DIM_, Bs + (cur^1)*4096 + 2048 + wid*512);
    }
    bf16x8 af[4], bf[4];
#pragma unroll
    for (int m=0;m<4;++m) af[m] = *(const bf16x8*)(As + cur*4096 + (64*wm+16*m+lr)*32 + rsw);
#pragma unroll
    for (int n=0;n<4;++n) bf[n] = *(const bf16x8*)(Bs + cur*4096 + (64*wn+16*n+lr)*32 + rsw);
    __builtin_amdgcn_s_setprio(1);
#pragma unroll
    for (int m=0;m<4;++m)
#pragma unroll
      for (int n=0;n<4;++n)
        acc[m][n] = __builtin_amdgcn_mfma_f32_16x16x32_bf16(af[m], bf[n], acc[m][n], 0, 0, 0);
    __builtin_amdgcn_s_setprio(0);
  }

  // unified epilogue: rows 64*wm+16m+4lg+r, head h, d = 16n+lr
  float gv[4];
#pragma unroll
  for (int n=0;n<4;++n)
    gv[n] = (qkv_t==0) ? g[16*n+lr]*(SCALE_*LOG2E_) : (qkv_t==1 ? g[16*n+lr] : 1.f);

#pragma unroll
  for (int m=0;m<4;++m){
    float rstd[4];
    if (qkv_t < 2){
#pragma unroll
      for (int r=0;r<4;++r){
        float s = 0.f;
#pragma unroll
        for (int n=0;n<4;++n) s += acc[m][n][r]*acc[m][n][r];
        s += __shfl_xor(s, 1); s += __shfl_xor(s, 2);
        s += __shfl_xor(s, 4); s += __shfl_xor(s, 8);
        rstd[r] = rsqrtf(s*(1.f/64.f) + 1e-6f);
      }
    } else {
#pragma unroll
      for (int r=0;r<4;++r) rstd[r] = 1.f;
    }
#pragma unroll
    for (int r=0;r<4;++r){
      int mg = m0 + 64*wm + 16*m + 4*lg + r;
      if (mg < M_){
        int b = mg / N_, pos = mg - b*N_;
        int bh = b*H_ + h;
#pragma unroll
        for (int n=0;n<4;++n){
          int d = 16*n + lr;
          u16 val = f2bf(acc[m][n][r]*rstd[r]*gv[n]);
          if (qkv_t == 0)
            qn[((size_t)bh*QP_ + pos)*64 + d] = val;
          else if (qkv_t == 1)
            kn2[(size_t)bh*KVSZ_ + (pos>>5)*2048 + ((d>>3)<<8) + ((pos&31)<<3) + (d&7)] = val;
          else
            v2[(size_t)bh*KVSZ_ + (pos>>5)*2048 + (((pos>>3)&3)<<9) + (d<<3) + (pos&7)] = val;
        }
      }
    }
  }
}

// ---------------- flash attention (merged main + cls) ----------------
// TILEP: verified tile body, base-pointer form (kb/vb = K/V tile bases in LDS)
#define TILEP(kb, vb, B0, B1) do { \
  f32x16 s; \
  _Pragma("unroll") \
  for (int r=0;r<16;++r){ \
    u16 bv = (r < 8) ? ((u16)(B0)[r]) : ((u16)(B1)[r-8]); \
    s[r] = __builtin_bit_cast(float, ((u32)bv) << 16); \
  } \
  __builtin_amdgcn_s_setprio(1); \
  _Pragma("unroll") \
  for (int c=0;c<4;++c){ \
    bf16x8 kf = *(const bf16x8*)((kb) + (2*c + hi)*256 + il*8); \
    s = __builtin_amdgcn_mfma_f32_32x32x16_bf16(kf, qf[c], s, 0, 0, 0); \
  } \
  __builtin_amdgcn_s_setprio(0); \
  _Pragma("unroll") \
  for (int r=0;r<16;++r) s[r] = __builtin_amdgcn_exp2f(s[r]); \
  u32 X0 = cvtpk(s[0],s[1]),   X1 = cvtpk(s[2],s[3]); \
  u32 Y0 = cvtpk(s[4],s[5]),   Y1 = cvtpk(s[6],s[7]); \
  u32 X2 = cvtpk(s[8],s[9]),   X3 = cvtpk(s[10],s[11]); \
  u32 Y2 = cvtpk(s[12],s[13]), Y3 = cvtpk(s[14],s[15]); \
  pswap(X0, Y0); pswap(X1, Y1); pswap(X2, Y2); pswap(X3, Y3); \
  u32x4 w0 = {X0, X1, Y0, Y1}; \
  u32x4 w1 = {X2, X3, Y2, Y3}; \
  bf16x8 pv0 = __builtin_bit_cast(bf16x8, w0); \
  bf16x8 pv1 = __builtin_bit_cast(bf16x8, w1); \
  __builtin_amdgcn_s_setprio(1); \
  _Pragma("unroll") \
  for (int c2=0;c2<2;++c2){ \
    bf16x8 pv = c2 ? pv1 : pv0; \
    const u16* vb2 = (vb) + (2*c2 + hi)*512; \
    bf16x8 vfA = *(const bf16x8*)(vb2 + il*8); \
    bf16x8 vfB = *(const bf16x8*)(vb2 + 256 + il*8); \
    oA = __builtin_amdgcn_mfma_f32_32x32x16_bf16(vfA, pv, oA, 0, 0, 0); \
    oB = __builtin_amdgcn_mfma_f32_32x32x16_bf16(vfB, pv, oB, 0, 0, 0); \
    oS = __builtin_amdgcn_mfma_f32_32x32x16_bf16(onesf, pv, oS, 0, 0, 0); \
  } \
  __builtin_amdgcn_s_setprio(0); \
} while(0)

// grid 2304: blocks [0,2048) = main (8 XCD-chunks x 32 b x 8 qt, rows 0..1023);
// blocks [2048,2304) = cls row 1024, split-j over 4 waves.
// red scratch ALIASES sh (cls K/V dead after loop) -> LDS exactly 32 KiB -> 5 blocks/CU.
__global__ __launch_bounds__(256, 3)
void k_attn2(const u16* __restrict__ qn, const u16* __restrict__ kn2, const u16* __restrict__ v2,
             const u16* __restrict__ br, u16* __restrict__ ao){
  __shared__ u16 sh[16384];          // main: K[2][4096] | V[2][4096]; cls: K[4][2048] | V[4][2048]
  const int tid = threadIdx.x;
  const int lane = tid & 63, wave = tid >> 6;
  const int il = lane & 31, hi = lane >> 5;
  u16* shK = sh;
  u16* shV = sh + 8192;

  f32x16 oA, oB, oS;
#pragma unroll
  for (int r=0;r<16;++r){ oA[r]=0.f; oB[r]=0.f; oS[r]=0.f; }
  const bf16x8 onesf = {0x3F80,0x3F80,0x3F80,0x3F80,0x3F80,0x3F80,0x3F80,0x3F80};

  if (blockIdx.x < 2048){
    // ---------------- main path ----------------
    int wg = ((blockIdx.x & 7) << 8) + (blockIdx.x >> 3);
    int h = wg >> 8;
    int rem = wg & 255;
    int b = rem >> 3, qt = rem & 7;
    int bh = b*8 + h;
    int i0 = qt*128 + wave*32;   // <= 992: all rows real

    const u16* qp = qn + ((size_t)bh*QP_ + (i0 + il))*64 + hi*8;
    bf16x8 qf[4];
#pragma unroll
    for (int c=0;c<4;++c) qf[c] = *(const bf16x8*)(qp + 16*c);

    const u16* ksrc = kn2 + (size_t)bh*KVSZ_ + tid*8;
    const u16* vsrc = v2  + (size_t)bh*KVSZ_ + tid*8;

    gll16(ksrc,        shK + wave*512);
    gll16(ksrc + 2048, shK + 2048 + wave*512);
    gll16(vsrc,        shV + wave*512);
    gll16(vsrc + 2048, shV + 2048 + wave*512);

    const u16* bptr = br + ((size_t)(h*NT_)*BIP_ + (i0 + il))*32 + hi*16;
    bf16x8 cb0 = *(const bf16x8*)(bptr);
    bf16x8 cb1 = *(const bf16x8*)(bptr + 8);
    bf16x8 cb2 = *(const bf16x8*)(bptr + BT_);
    bf16x8 cb3 = *(const bf16x8*)(bptr + BT_ + 8);

    for (int t=0; t<16; ++t){
      const int cur = t & 1;
      __syncthreads();
      {
        const int base = (2*t+2)*2048;   // t=15 -> tiles 32,33 (pad tile valid)
        gll16(ksrc + base,        shK + (cur^1)*4096 + wave*512);
        gll16(ksrc + base + 2048, shK + (cur^1)*4096 + 2048 + wave*512);
        gll16(vsrc + base,        shV + (cur^1)*4096 + wave*512);
        gll16(vsrc + base + 2048, shV + (cur^1)*4096 + 2048 + wave*512);
      }
      TILEP(shK + cur*4096,        shV + cur*4096,        cb0, cb1);
      cb0 = *(const bf16x8*)(bptr + 2*BT_);
      cb1 = *(const bf16x8*)(bptr + 2*BT_ + 8);
      TILEP(shK + cur*4096 + 2048, shV + cur*4096 + 2048, cb2, cb3);
      cb2 = *(const bf16x8*)(bptr + 3*BT_);
      cb3 = *(const bf16x8*)(bptr + 3*BT_ + 8);
      bptr += 2*BT_;
    }
    __syncthreads();
    TILEP(shK, shV, cb0, cb1);   // tail: tile 32 in buf 0

    float inv = 1.f / oS[0];
    int i = i0 + il;
    u16* op = ao + ((size_t)(b*N_ + i))*DIM_ + h*64;
#pragma unroll
    for (int q=0;q<4;++q)
#pragma unroll
      for (int pr=0;pr<2;++pr){
        int d0 = 8*q + 4*hi + 2*pr;
        u32 wA = cvtpk(oA[4*q+2*pr]*inv, oA[4*q+2*pr+1]*inv);
        u32 wB = cvtpk(oB[4*q+2*pr]*inv, oB[4*q+2*pr+1]*inv);
        *(u32*)(op + d0) = wA;
        *(u32*)(op + 32 + d0) = wB;
      }
  } else {
    // ---------------- cls path: row 1024, split-j over 4 waves ----------------
    int idx2 = blockIdx.x - 2048;       // 0..255; xcd = idx2&7 = h (bias locality)
    int h = idx2 & 7, b = idx2 >> 3;
    int bh = b*8 + h;

    const u16* qp = qn + ((size_t)bh*QP_ + (1024 + il))*64 + hi*8;
    bf16x8 qf[4];
#pragma unroll
    for (int c=0;c<4;++c) qf[c] = *(const bf16x8*)(qp + 16*c);

    const u16* ksrc = kn2 + (size_t)bh*KVSZ_ + tid*8;
    const u16* vsrc = v2  + (size_t)bh*KVSZ_ + tid*8;

    for (int rr=0; rr<9; ++rr){
      __syncthreads();       // previous round's compute done
#pragma unroll
      for (int tt=0;tt<4;++tt){
        int t = 4*rr + tt;
        if (t < NT_){
          gll16(ksrc + t*2048, shK + tt*2048 + wave*512);
          gll16(vsrc + t*2048, shV + tt*2048 + wave*512);
        }
      }
      __syncthreads();       // staging landed (vmcnt drained by barrier)
      const int t = 4*rr + wave;
      if (t <= 32){
        const u16* bp2 = br + ((size_t)(h*NT_ + t)*BIP_ + (1024 + il))*32 + hi*16;
        bf16x8 c0 = *(const bf16x8*)(bp2);
        bf16x8 c1 = *(const bf16x8*)(bp2 + 8);
        TILEP(shK + wave*2048, shV + wave*2048, c0, c1);
      }
    }

    // combine 4 waves' disjoint-tile partials; red scratch aliases sh (K/V dead)
    float* red_ = (float*)sh;           // [4][2][33]
    __syncthreads();                    // all waves done reading shK/shV
    if (il == 0){
#pragma unroll
      for (int r=0;r<16;++r){
        red_[(wave*2 + hi)*33 + r]      = oA[r];
        red_[(wave*2 + hi)*33 + 16 + r] = oB[r];
      }
      red_[(wave*2 + hi)*33 + 32] = oS[0];
    }
    __syncthreads();
    if (tid < 64){
      int d = tid;
      int half = d >> 5;
      int dd = d & 31;
      int q = dd >> 3, h2 = (dd >> 2) & 1, pr = (dd >> 1) & 1, e = dd & 1;
      int reg = half*16 + 4*q + 2*pr + e;
      float v = 0.f, ls = 0.f;
#pragma unroll
      for (int w=0; w<4; ++w){ v += red_[(w*2 + h2)*33 + reg]; ls += red_[(w*2)*33 + 32]; }
      ao[((size_t)(b*N_ + 1024))*DIM_ + h*64 + d] = f2bf(v / ls);
    }
  }
}

// ---------------- output projection (128x128 tile) ----------------
// grid 1028 = 257 x 4
__global__ __launch_bounds__(256)
void k_oproj(const u16* __restrict__ ab, const u16* __restrict__ wT, const float* __restrict__ bo,
             float* __restrict__ out){
  __shared__ u16 sh[16384];
  const int tid = threadIdx.x;
  const int lane = tid & 63, wid = tid >> 6;
  const int lg = lane >> 4, lr = lane & 15;
  const int wm = wid >> 1, wn = wid & 1;

  // bijective XCD swizzle (nwg=1028, q=128, r=4)
  int orig = blockIdx.x;
  int xcd = orig & 7, idx = orig >> 3;
  int wgid = (xcd < 4 ? xcd*129 : 516 + (xcd-4)*128) + idx;
  int mt = wgid >> 2, nt = wgid & 3;
  const int m0 = mt*128, n0 = nt*128;

  const int srow = tid >> 2;
  const int schunk = (tid & 3) ^ ((tid >> 3) & 3);
  const u16* asrc = ab + (size_t)(m0 + srow)*DIM_ + schunk*8;
  const u16* bsrc = wT + (size_t)(n0 + srow)*DIM_ + schunk*8;
  const int rsw = (lg ^ ((lr>>1)&3)) << 3;

  u16* As = sh;
  u16* Bs = sh + 8192;

  f32x4 acc[4][4];
#pragma unroll
  for (int m=0;m<4;++m)
#pragma unroll
    for (int n=0;n<4;++n) acc[m][n] = {0.f,0.f,0.f,0.f};

  gll16(asrc,            As + wid*512);
  gll16(asrc + 64*DIM_,  As + 2048 + wid*512);
  gll16(bsrc,            Bs + wid*512);
  gll16(bsrc + 64*DIM_,  Bs + 2048 + wid*512);

  for (int s=0; s<16; ++s){
    const int cur = s & 1;
    __syncthreads();
    if (s < 15){
      const int ko = (s+1)*32;
      gll16(asrc + ko,           As + (cur^1)*4096 + wid*512);
      gll16(asrc + ko + 64*DIM_, As + (cur^1)*4096 + 2048 + wid*512);
      gll16(bsrc + ko,           Bs + (cur^1)*4096 + wid*512);
      gll16(bsrc + ko + 64*DIM_, Bs + (cur^1)*4096 + 2048 + wid*512);
    }
    bf16x8 af[4], bf[4];
#pragma unroll
    for (int m=0;m<4;++m) af[m] = *(const bf16x8*)(As + cur*4096 + (64*wm+16*m+lr)*32 + rsw);
#pragma unroll
    for (int n=0;n<4;++n) bf[n] = *(const bf16x8*)(Bs + cur*4096 + (64*wn+16*n+lr)*32 + rsw);
    __builtin_amdgcn_s_setprio(1);
#pragma unroll
    for (int m=0;m<4;++m)
#pragma unroll
      for (int n=0;n<4;++n)
        acc[m][n] = __builtin_amdgcn_mfma_f32_16x16x32_bf16(af[m], bf[n], acc[m][n], 0, 0, 0);
    __builtin_amdgcn_s_setprio(0);
  }

  float bb[4];
#pragma unroll
  for (int n=0;n<4;++n) bb[n] = bo[n0 + 64*wn + 16*n + lr];
#pragma unroll
  for (int m=0;m<4;++m)
#pragma unroll
    for (int r=0;r<4;++r){
      int mg = m0 + 64*wm + 16*m + 4*lg + r;
      if (mg < M_){
#pragma unroll
        for (int n=0;n<4;++n)
          out[(size_t)mg*DIM_ + n0 + 64*wn + 16*n + lr] = acc[m][n][r] + bb[n];
      }
    }
}

// ---------------- launch ----------------
extern "C" void kernel_launch(void* const* d_in, const int* in_sizes, int n_in,
                              void* d_out, int out_size, void* d_ws, size_t ws_size,
                              hipStream_t stream) {
  const float* x     = (const float*)d_in[0];
  const float* w_qkv = (const float*)d_in[1];
  const float* g     = (const float*)d_in[2];
  const float* pe    = (const float*)d_in[3];
  const float* w_out = (const float*)d_in[4];
  const float* b_out = (const float*)d_in[5];
  const int*   bidx  = (const int*)d_in[6];
  float* out = (float*)d_out;

  char* ws = (char*)d_ws;
  u16*   xb    = (u16*)(ws);                    // 33,587,200  (aliased: aob reuses after k_qkv)
  u16*   wT    = (u16*)(ws + 33587200);         //  1,572,864
  u16*   woT   = (u16*)(ws + 35160064);         //    524,288
  u16*   qnb   = (u16*)(ws + 35684352);         // 37,748,736
  u16*   kn2   = (u16*)(ws + 73433088);         // 35,651,584
  u16*   v2    = (u16*)(ws + 109084672);        // 35,651,584
  u16*   biasr = (u16*)(ws + 144736256);        // 20,054,016  (end 164,790,272)
  u16*   aob   = xb;                            // alias: xb dead after k_qkv

  k_prep<<<PREP_TOTAL_/256, 256, 0, stream>>>(x, w_qkv, w_out, bidx, pe,
                                              xb, wT, woT, biasr, qnb, kn2, v2);
  k_qkv<<<3084, 256, 0, stream>>>(xb, wT, g, qnb, kn2, v2);
  k_attn2<<<2304, 256, 0, stream>>>(qnb, kn2, v2, biasr, aob);
  k_oproj<<<1028, 256, 0, stream>>>(aob, woT, b_out, out);
}

// Round 18
// 266.297 us; speedup vs baseline: 1.0685x; 1.0244x over previous
//
#include <hip/hip_runtime.h>

typedef short bf16x8 __attribute__((ext_vector_type(8)));
typedef float f32x4 __attribute__((ext_vector_type(4)));
typedef float f32x16 __attribute__((ext_vector_type(16)));
typedef unsigned int u32;
typedef u32 u32x4 __attribute__((ext_vector_type(4)));
typedef unsigned short u16;

#define B_    32
#define N_    1025
#define H_    8
#define DIM_  512
#define M_    (B_*N_)      // 32800
#define QP_   1152         // qn row pitch per bh
#define BIP_  1152         // bias_r i pitch
#define NT_   34           // KV/bias tiles incl. 1 pad tile (prefetch guard-free)
#define KVSZ_ (NT_*2048)   // per-bh u16 size of kn2/v2
#define BT_   (BIP_*32)    // bias tile stride (u16 elements)
#define SCALE_ 0.125f
#define LOG2E_ 1.4426950408889634f

// fused-prep section sizes (bias section: 8 outputs/thread)
#define CONVN_ (M_*DIM_/4)          // 4,198,400
#define TQKV_  (512*1536)           // 786,432
#define TOUT_  (512*512)            // 262,144
#define NBIAS8_ (8*NT_*1152*32/8)   // 1,253,376 threads (x8 outputs)
#define NZT_   3096576
#define PREP_TOTAL_ (CONVN_+TQKV_+TOUT_+NBIAS8_+NZT_)   // 9,596,928 -> 37,488 blocks

__device__ __forceinline__ u16 f2bf(float f){
  unsigned u = __builtin_bit_cast(unsigned, f);
  u += 0x7FFFu + ((u >> 16) & 1u);
  return (u16)(u >> 16);
}
__device__ __forceinline__ u32 cvtpk(float a, float b){
  u32 r;
  asm("v_cvt_pk_bf16_f32 %0, %1, %2" : "=v"(r) : "v"(a), "v"(b));
  return r;
}
__device__ __forceinline__ void pswap(u32 &a, u32 &b){
  asm("v_permlane32_swap_b32 %0, %1" : "+v"(a), "+v"(b));
}
__device__ __forceinline__ void gll16(const u16* g, u16* l){
  __builtin_amdgcn_global_load_lds((const __attribute__((address_space(1))) u16*)(g),
                                   (__attribute__((address_space(3))) u16*)(l), 16, 0, 0);
}

// ---------------- fused prep kernel ----------------
__global__ __launch_bounds__(256)
void k_prep(const float* __restrict__ x, const float* __restrict__ wqkv,
            const float* __restrict__ wout, const int* __restrict__ idx,
            const float* __restrict__ pe,
            u16* __restrict__ xb, u16* __restrict__ wT, u16* __restrict__ woT,
            u16* __restrict__ br,
            u16* __restrict__ qn, u16* __restrict__ kn2, u16* __restrict__ v2){
  int i = blockIdx.x*256 + threadIdx.x;
  if (i < CONVN_){
    float4 v = ((const float4*)x)[i];
    ushort4 r;
    r.x = f2bf(v.x); r.y = f2bf(v.y); r.z = f2bf(v.z); r.w = f2bf(v.w);
    ((ushort4*)xb)[i] = r;
  } else if (i < CONVN_+TQKV_){
    int j = i - CONVN_;
    int n = j / 512, k = j - n*512;
    wT[j] = f2bf(wqkv[k*1536 + n]);
  } else if (i < CONVN_+TQKV_+TOUT_){
    int j = i - (CONVN_+TQKV_);
    int n = j / 512, k = j - n*512;
    woT[j] = f2bf(wout[k*512 + n]);
  } else if (i < CONVN_+TQKV_+TOUT_+NBIAS8_){
    // 8 consecutive table entries per thread: t -> outputs [8t, 8t+8)
    int t = i - (CONVN_+TQKV_+TOUT_);
    int hi = (t >> 1) & 1;
    int t1 = t >> 2;                  // (8t+e)>>5
    int ii = t1 % 1152;
    int t2 = t1 / 1152;
    int tj = t2 % NT_;
    int h = t2 / NT_;
    bf16x8 outv;
#pragma unroll
    for (int e=0; e<8; ++e){
      int v = 8*(t & 1) + e;
      int jj = tj*32 + (v & 3) + 8*(v >> 2) + 4*hi;
      float val;
      if (jj >= 1 && jj <= 1024 && ii >= 1 && ii <= 1024)
        val = pe[idx[(ii-1)*1024 + (jj-1)]*8 + h] * LOG2E_;
      else
        val = (jj <= 1024) ? 0.f : -1e9f;
      outv[e] = (short)f2bf(val);
    }
    *(bf16x8*)(br + (size_t)t*8) = outv;
  } else {
    int j = i - (CONVN_+TQKV_+TOUT_+NBIAS8_);
    if (j < 2080768){
      int bh = j / (127*64); int r = j - bh*(127*64);
      qn[((size_t)bh*QP_ + 1025 + (r>>6))*64 + (r&63)] = 0;
    } else if (j < 2588672){
      int k = j - 2080768; int bh = k/1984; int r = k - bh*1984;
      int n = 1025 + (r>>6), d = r & 63;
      kn2[(size_t)bh*KVSZ_ + 65536 + ((d>>3)<<8) + ((n&31)<<3) + (d&7)] = 0;
    } else if (j < 3096576){
      int k = j - 2588672; int bh = k/1984; int r = k - bh*1984;
      int n = 1025 + (r>>6), d = r & 63;
      v2[(size_t)bh*KVSZ_ + 65536 + (((n>>3)&3)<<9) + (d<<3) + (n&7)] = 0;
    }
  }
}

// ---------------- QKV GEMM (128x128 tile) + fused RMSNorm / rearrange ----------------
// grid 3084 = 257 M-tiles x 12 N-tiles; 4 waves 2x2, each 64x64 quadrant
__global__ __launch_bounds__(256, 4)
void k_qkv(const u16* __restrict__ xb, const u16* __restrict__ wT, const float* __restrict__ g,
           u16* __restrict__ qn, u16* __restrict__ kn2, u16* __restrict__ v2){
  __shared__ u16 sh[16384];   // As[2][4096] | Bs[2][4096]
  const int tid = threadIdx.x;
  const int lane = tid & 63, wid = tid >> 6;
  const int lg = lane >> 4, lr = lane & 15;
  const int wm = wid >> 1, wn = wid & 1;

  // bijective XCD swizzle (nwg=3084, q=385, r=4); within XCD: nt fastest
  int orig = blockIdx.x;
  int xcd = orig & 7, idx = orig >> 3;
  int wgid = (xcd < 4 ? xcd*386 : 1544 + (xcd-4)*385) + idx;
  int mt = wgid / 12, nt = wgid - mt*12;
  const int m0 = mt*128, n0 = nt*128;
  const int qkv_t = nt >> 2;
  const int h = ((nt & 3) << 1) + wn;

  const int srow = tid >> 2;
  const int schunk = (tid & 3) ^ ((tid >> 3) & 3);
  const u16* asrc = xb + (size_t)(m0 + srow)*DIM_ + schunk*8;
  const u16* bsrc = wT + (size_t)(n0 + srow)*DIM_ + schunk*8;
  const int rsw = (lg ^ ((lr>>1)&3)) << 3;

  u16* As = sh;
  u16* Bs = sh + 8192;

  f32x4 acc[4][4];
#pragma unroll
  for (int m=0;m<4;++m)
#pragma unroll
    for (int n=0;n<4;++n) acc[m][n] = {0.f,0.f,0.f,0.f};

  gll16(asrc,            As + wid*512);
  gll16(asrc + 64*DIM_,  As + 2048 + wid*512);
  gll16(bsrc,            Bs + wid*512);
  gll16(bsrc + 64*DIM_,  Bs + 2048 + wid*512);

  for (int s=0; s<16; ++s){
    const int cur = s & 1;
    __syncthreads();
    if (s < 15){
      const int ko = (s+1)*32;
      gll16(asrc + ko,           As + (cur^1)*4096 + wid*512);
      gll16(asrc + ko + 64*DIM_, As + (cur^1)*4096 + 2048 + wid*512);
      gll16(bsrc + ko,           Bs + (cur^1)*4096 + wid*512);
      gll16(bsrc + ko + 64*DIM_, Bs + (cur^1)*4096 + 2048 + wid*512);
    }
    bf16x8 af[4], bf[4];
#pragma unroll
    for (int m=0;m<4;++m) af[m] = *(const bf16x8*)(As + cur*4096 + (64*wm+16*m+lr)*32 + rsw);
#pragma unroll
    for (int n=0;n<4;++n) bf[n] = *(const bf16x8*)(Bs + cur*4096 + (64*wn+16*n+lr)*32 + rsw);
    __builtin_amdgcn_s_setprio(1);
#pragma unroll
    for (int m=0;m<4;++m)
#pragma unroll
      for (int n=0;n<4;++n)
        acc[m][n] = __builtin_amdgcn_mfma_f32_16x16x32_bf16(af[m], bf[n], acc[m][n], 0, 0, 0);
    __builtin_amdgcn_s_setprio(0);
  }

  // unified epilogue: rows 64*wm+16m+4lg+r, head h, d = 16n+lr
  float gv[4];
#pragma unroll
  for (int n=0;n<4;++n)
    gv[n] = (qkv_t==0) ? g[16*n+lr]*(SCALE_*LOG2E_) : (qkv_t==1 ? g[16*n+lr] : 1.f);

#pragma unroll
  for (int m=0;m<4;++m){
    float rstd[4];
    if (qkv_t < 2){
#pragma unroll
      for (int r=0;r<4;++r){
        float s = 0.f;
#pragma unroll
        for (int n=0;n<4;++n) s += acc[m][n][r]*acc[m][n][r];
        s += __shfl_xor(s, 1); s += __shfl_xor(s, 2);
        s += __shfl_xor(s, 4); s += __shfl_xor(s, 8);
        rstd[r] = rsqrtf(s*(1.f/64.f) + 1e-6f);
      }
    } else {
#pragma unroll
      for (int r=0;r<4;++r) rstd[r] = 1.f;
    }
#pragma unroll
    for (int r=0;r<4;++r){
      int mg = m0 + 64*wm + 16*m + 4*lg + r;
      if (mg < M_){
        int b = mg / N_, pos = mg - b*N_;
        int bh = b*H_ + h;
#pragma unroll
        for (int n=0;n<4;++n){
          int d = 16*n + lr;
          u16 val = f2bf(acc[m][n][r]*rstd[r]*gv[n]);
          if (qkv_t == 0)
            qn[((size_t)bh*QP_ + pos)*64 + d] = val;
          else if (qkv_t == 1)
            kn2[(size_t)bh*KVSZ_ + (pos>>5)*2048 + ((d>>3)<<8) + ((pos&31)<<3) + (d&7)] = val;
          else
            v2[(size_t)bh*KVSZ_ + (pos>>5)*2048 + (((pos>>3)&3)<<9) + (d<<3) + (pos&7)] = val;
        }
      }
    }
  }
}

// ---------------- flash attention (merged main + cls) ----------------
// TILEP: verified tile body, base-pointer form (kb/vb = K/V tile bases in LDS)
#define TILEP(kb, vb, B0, B1) do { \
  f32x16 s; \
  _Pragma("unroll") \
  for (int r=0;r<16;++r){ \
    u16 bv = (r < 8) ? ((u16)(B0)[r]) : ((u16)(B1)[r-8]); \
    s[r] = __builtin_bit_cast(float, ((u32)bv) << 16); \
  } \
  __builtin_amdgcn_s_setprio(1); \
  _Pragma("unroll") \
  for (int c=0;c<4;++c){ \
    bf16x8 kf = *(const bf16x8*)((kb) + (2*c + hi)*256 + il*8); \
    s = __builtin_amdgcn_mfma_f32_32x32x16_bf16(kf, qf[c], s, 0, 0, 0); \
  } \
  __builtin_amdgcn_s_setprio(0); \
  _Pragma("unroll") \
  for (int r=0;r<16;++r) s[r] = __builtin_amdgcn_exp2f(s[r]); \
  u32 X0 = cvtpk(s[0],s[1]),   X1 = cvtpk(s[2],s[3]); \
  u32 Y0 = cvtpk(s[4],s[5]),   Y1 = cvtpk(s[6],s[7]); \
  u32 X2 = cvtpk(s[8],s[9]),   X3 = cvtpk(s[10],s[11]); \
  u32 Y2 = cvtpk(s[12],s[13]), Y3 = cvtpk(s[14],s[15]); \
  pswap(X0, Y0); pswap(X1, Y1); pswap(X2, Y2); pswap(X3, Y3); \
  u32x4 w0 = {X0, X1, Y0, Y1}; \
  u32x4 w1 = {X2, X3, Y2, Y3}; \
  bf16x8 pv0 = __builtin_bit_cast(bf16x8, w0); \
  bf16x8 pv1 = __builtin_bit_cast(bf16x8, w1); \
  __builtin_amdgcn_s_setprio(1); \
  _Pragma("unroll") \
  for (int c2=0;c2<2;++c2){ \
    bf16x8 pv = c2 ? pv1 : pv0; \
    const u16* vb2 = (vb) + (2*c2 + hi)*512; \
    bf16x8 vfA = *(const bf16x8*)(vb2 + il*8); \
    bf16x8 vfB = *(const bf16x8*)(vb2 + 256 + il*8); \
    oA = __builtin_amdgcn_mfma_f32_32x32x16_bf16(vfA, pv, oA, 0, 0, 0); \
    oB = __builtin_amdgcn_mfma_f32_32x32x16_bf16(vfB, pv, oB, 0, 0, 0); \
    oS = __builtin_amdgcn_mfma_f32_32x32x16_bf16(onesf, pv, oS, 0, 0, 0); \
  } \
  __builtin_amdgcn_s_setprio(0); \
} while(0)

// grid 2304: blocks [0,2048) = main (8 XCD-chunks x 32 b x 8 qt, rows 0..1023);
// blocks [2048,2304) = cls row 1024, split-j over 4 waves.
// red scratch ALIASES sh (cls K/V dead after loop) -> LDS exactly 32 KiB -> 5 blocks/CU.
__global__ __launch_bounds__(256, 3)
void k_attn2(const u16* __restrict__ qn, const u16* __restrict__ kn2, const u16* __restrict__ v2,
             const u16* __restrict__ br, u16* __restrict__ ao){
  __shared__ u16 sh[16384];          // main: K[2][4096] | V[2][4096]; cls: K[4][2048] | V[4][2048]
  const int tid = threadIdx.x;
  const int lane = tid & 63, wave = tid >> 6;
  const int il = lane & 31, hi = lane >> 5;
  u16* shK = sh;
  u16* shV = sh + 8192;

  f32x16 oA, oB, oS;
#pragma unroll
  for (int r=0;r<16;++r){ oA[r]=0.f; oB[r]=0.f; oS[r]=0.f; }
  const bf16x8 onesf = {0x3F80,0x3F80,0x3F80,0x3F80,0x3F80,0x3F80,0x3F80,0x3F80};

  if (blockIdx.x < 2048){
    // ---------------- main path ----------------
    int wg = ((blockIdx.x & 7) << 8) + (blockIdx.x >> 3);
    int h = wg >> 8;
    int rem = wg & 255;
    int b = rem >> 3, qt = rem & 7;
    int bh = b*8 + h;
    int i0 = qt*128 + wave*32;   // <= 992: all rows real

    const u16* qp = qn + ((size_t)bh*QP_ + (i0 + il))*64 + hi*8;
    bf16x8 qf[4];
#pragma unroll
    for (int c=0;c<4;++c) qf[c] = *(const bf16x8*)(qp + 16*c);

    const u16* ksrc = kn2 + (size_t)bh*KVSZ_ + tid*8;
    const u16* vsrc = v2  + (size_t)bh*KVSZ_ + tid*8;

    gll16(ksrc,        shK + wave*512);
    gll16(ksrc + 2048, shK + 2048 + wave*512);
    gll16(vsrc,        shV + wave*512);
    gll16(vsrc + 2048, shV + 2048 + wave*512);

    const u16* bptr = br + ((size_t)(h*NT_)*BIP_ + (i0 + il))*32 + hi*16;
    bf16x8 cb0 = *(const bf16x8*)(bptr);
    bf16x8 cb1 = *(const bf16x8*)(bptr + 8);
    bf16x8 cb2 = *(const bf16x8*)(bptr + BT_);
    bf16x8 cb3 = *(const bf16x8*)(bptr + BT_ + 8);

    for (int t=0; t<16; ++t){
      const int cur = t & 1;
      __syncthreads();
      {
        const int base = (2*t+2)*2048;   // t=15 -> tiles 32,33 (pad tile valid)
        gll16(ksrc + base,        shK + (cur^1)*4096 + wave*512);
        gll16(ksrc + base + 2048, shK + (cur^1)*4096 + 2048 + wave*512);
        gll16(vsrc + base,        shV + (cur^1)*4096 + wave*512);
        gll16(vsrc + base + 2048, shV + (cur^1)*4096 + 2048 + wave*512);
      }
      TILEP(shK + cur*4096,        shV + cur*4096,        cb0, cb1);
      cb0 = *(const bf16x8*)(bptr + 2*BT_);
      cb1 = *(const bf16x8*)(bptr + 2*BT_ + 8);
      TILEP(shK + cur*4096 + 2048, shV + cur*4096 + 2048, cb2, cb3);
      cb2 = *(const bf16x8*)(bptr + 3*BT_);
      cb3 = *(const bf16x8*)(bptr + 3*BT_ + 8);
      bptr += 2*BT_;
    }
    __syncthreads();
    TILEP(shK, shV, cb0, cb1);   // tail: tile 32 in buf 0

    float inv = 1.f / oS[0];
    int i = i0 + il;
    u16* op = ao + ((size_t)(b*N_ + i))*DIM_ + h*64;
#pragma unroll
    for (int q=0;q<4;++q)
#pragma unroll
      for (int pr=0;pr<2;++pr){
        int d0 = 8*q + 4*hi + 2*pr;
        u32 wA = cvtpk(oA[4*q+2*pr]*inv, oA[4*q+2*pr+1]*inv);
        u32 wB = cvtpk(oB[4*q+2*pr]*inv, oB[4*q+2*pr+1]*inv);
        *(u32*)(op + d0) = wA;
        *(u32*)(op + 32 + d0) = wB;
      }
  } else {
    // ---------------- cls path: row 1024, split-j over 4 waves ----------------
    int idx2 = blockIdx.x - 2048;       // 0..255; xcd = idx2&7 = h (bias locality)
    int h = idx2 & 7, b = idx2 >> 3;
    int bh = b*8 + h;

    const u16* qp = qn + ((size_t)bh*QP_ + (1024 + il))*64 + hi*8;
    bf16x8 qf[4];
#pragma unroll
    for (int c=0;c<4;++c) qf[c] = *(const bf16x8*)(qp + 16*c);

    const u16* ksrc = kn2 + (size_t)bh*KVSZ_ + tid*8;
    const u16* vsrc = v2  + (size_t)bh*KVSZ_ + tid*8;

    for (int rr=0; rr<9; ++rr){
      __syncthreads();       // previous round's compute done
#pragma unroll
      for (int tt=0;tt<4;++tt){
        int t = 4*rr + tt;
        if (t < NT_){
          gll16(ksrc + t*2048, shK + tt*2048 + wave*512);
          gll16(vsrc + t*2048, shV + tt*2048 + wave*512);
        }
      }
      __syncthreads();       // staging landed (vmcnt drained by barrier)
      const int t = 4*rr + wave;
      if (t <= 32){
        const u16* bp2 = br + ((size_t)(h*NT_ + t)*BIP_ + (1024 + il))*32 + hi*16;
        bf16x8 c0 = *(const bf16x8*)(bp2);
        bf16x8 c1 = *(const bf16x8*)(bp2 + 8);
        TILEP(shK + wave*2048, shV + wave*2048, c0, c1);
      }
    }

    // combine 4 waves' disjoint-tile partials; red scratch aliases sh (K/V dead)
    float* red_ = (float*)sh;           // [4][2][33]
    __syncthreads();                    // all waves done reading shK/shV
    if (il == 0){
#pragma unroll
      for (int r=0;r<16;++r){
        red_[(wave*2 + hi)*33 + r]      = oA[r];
        red_[(wave*2 + hi)*33 + 16 + r] = oB[r];
      }
      red_[(wave*2 + hi)*33 + 32] = oS[0];
    }
    __syncthreads();
    if (tid < 64){
      int d = tid;
      int half = d >> 5;
      int dd = d & 31;
      int q = dd >> 3, h2 = (dd >> 2) & 1, pr = (dd >> 1) & 1, e = dd & 1;
      int reg = half*16 + 4*q + 2*pr + e;
      float v = 0.f, ls = 0.f;
#pragma unroll
      for (int w=0; w<4; ++w){ v += red_[(w*2 + h2)*33 + reg]; ls += red_[(w*2)*33 + 32]; }
      ao[((size_t)(b*N_ + 1024))*DIM_ + h*64 + d] = f2bf(v / ls);
    }
  }
}

// ---------------- output projection (128x128 tile) ----------------
// grid 1028 = 257 x 4
__global__ __launch_bounds__(256, 4)
void k_oproj(const u16* __restrict__ ab, const u16* __restrict__ wT, const float* __restrict__ bo,
             float* __restrict__ out){
  __shared__ u16 sh[16384];
  const int tid = threadIdx.x;
  const int lane = tid & 63, wid = tid >> 6;
  const int lg = lane >> 4, lr = lane & 15;
  const int wm = wid >> 1, wn = wid & 1;

  // bijective XCD swizzle (nwg=1028, q=128, r=4)
  int orig = blockIdx.x;
  int xcd = orig & 7, idx = orig >> 3;
  int wgid = (xcd < 4 ? xcd*129 : 516 + (xcd-4)*128) + idx;
  int mt = wgid >> 2, nt = wgid & 3;
  const int m0 = mt*128, n0 = nt*128;

  const int srow = tid >> 2;
  const int schunk = (tid & 3) ^ ((tid >> 3) & 3);
  const u16* asrc = ab + (size_t)(m0 + srow)*DIM_ + schunk*8;
  const u16* bsrc = wT + (size_t)(n0 + srow)*DIM_ + schunk*8;
  const int rsw = (lg ^ ((lr>>1)&3)) << 3;

  u16* As = sh;
  u16* Bs = sh + 8192;

  f32x4 acc[4][4];
#pragma unroll
  for (int m=0;m<4;++m)
#pragma unroll
    for (int n=0;n<4;++n) acc[m][n] = {0.f,0.f,0.f,0.f};

  gll16(asrc,            As + wid*512);
  gll16(asrc + 64*DIM_,  As + 2048 + wid*512);
  gll16(bsrc,            Bs + wid*512);
  gll16(bsrc + 64*DIM_,  Bs + 2048 + wid*512);

  for (int s=0; s<16; ++s){
    const int cur = s & 1;
    __syncthreads();
    if (s < 15){
      const int ko = (s+1)*32;
      gll16(asrc + ko,           As + (cur^1)*4096 + wid*512);
      gll16(asrc + ko + 64*DIM_, As + (cur^1)*4096 + 2048 + wid*512);
      gll16(bsrc + ko,           Bs + (cur^1)*4096 + wid*512);
      gll16(bsrc + ko + 64*DIM_, Bs + (cur^1)*4096 + 2048 + wid*512);
    }
    bf16x8 af[4], bf[4];
#pragma unroll
    for (int m=0;m<4;++m) af[m] = *(const bf16x8*)(As + cur*4096 + (64*wm+16*m+lr)*32 + rsw);
#pragma unroll
    for (int n=0;n<4;++n) bf[n] = *(const bf16x8*)(Bs + cur*4096 + (64*wn+16*n+lr)*32 + rsw);
    __builtin_amdgcn_s_setprio(1);
#pragma unroll
    for (int m=0;m<4;++m)
#pragma unroll
      for (int n=0;n<4;++n)
        acc[m][n] = __builtin_amdgcn_mfma_f32_16x16x32_bf16(af[m], bf[n], acc[m][n], 0, 0, 0);
    __builtin_amdgcn_s_setprio(0);
  }

  float bb[4];
#pragma unroll
  for (int n=0;n<4;++n) bb[n] = bo[n0 + 64*wn + 16*n + lr];
#pragma unroll
  for (int m=0;m<4;++m)
#pragma unroll
    for (int r=0;r<4;++r){
      int mg = m0 + 64*wm + 16*m + 4*lg + r;
      if (mg < M_){
#pragma unroll
        for (int n=0;n<4;++n)
          out[(size_t)mg*DIM_ + n0 + 64*wn + 16*n + lr] = acc[m][n][r] + bb[n];
      }
    }
}

// ---------------- launch ----------------
extern "C" void kernel_launch(void* const* d_in, const int* in_sizes, int n_in,
                              void* d_out, int out_size, void* d_ws, size_t ws_size,
                              hipStream_t stream) {
  const float* x     = (const float*)d_in[0];
  const float* w_qkv = (const float*)d_in[1];
  const float* g     = (const float*)d_in[2];
  const float* pe    = (const float*)d_in[3];
  const float* w_out = (const float*)d_in[4];
  const float* b_out = (const float*)d_in[5];
  const int*   bidx  = (const int*)d_in[6];
  float* out = (float*)d_out;

  char* ws = (char*)d_ws;
  u16*   xb    = (u16*)(ws);                    // 33,587,200  (aliased: aob reuses after k_qkv)
  u16*   wT    = (u16*)(ws + 33587200);         //  1,572,864
  u16*   woT   = (u16*)(ws + 35160064);         //    524,288
  u16*   qnb   = (u16*)(ws + 35684352);         // 37,748,736
  u16*   kn2   = (u16*)(ws + 73433088);         // 35,651,584
  u16*   v2    = (u16*)(ws + 109084672);        // 35,651,584
  u16*   biasr = (u16*)(ws + 144736256);        // 20,054,016  (end 164,790,272)
  u16*   aob   = xb;                            // alias: xb dead after k_qkv

  k_prep<<<PREP_TOTAL_/256, 256, 0, stream>>>(x, w_qkv, w_out, bidx, pe,
                                              xb, wT, woT, biasr, qnb, kn2, v2);
  k_qkv<<<3084, 256, 0, stream>>>(xb, wT, g, qnb, kn2, v2);
  k_attn2<<<2304, 256, 0, stream>>>(qnb, kn2, v2, biasr, aob);
  k_oproj<<<1028, 256, 0, stream>>>(aob, woT, b_out, out);
}